// Round 2
// baseline (1071.150 us; speedup 1.0000x reference)
//
#include <hip/hip_runtime.h>
#include <hip/hip_bf16.h>

// AGIFORMERBlock: B=2, S=2048, D=1024, H=16 (dh=64), F=4096, E=8, K=2
constexpr int Sc = 2048;
constexpr int Dc = 1024;
constexpr int Fc = 4096;
constexpr int Ec = 8;
constexpr int NTOK = 4096;  // B*S

typedef __attribute__((ext_vector_type(8))) short short8;
typedef __attribute__((ext_vector_type(4))) float floatx4;
typedef unsigned short u16;

__device__ __forceinline__ u16 f2bf(float f) {
    __hip_bfloat16 h = __float2bfloat16(f);
    return *reinterpret_cast<u16*>(&h);
}

// tanh-gelu via sigmoid identity: 0.5x(1+tanh(y)) = x * 1/(1+exp(-2y)),
// y = 0.79788456(x + 0.044715 x^3)  ->  -2y = x*(-1.59576912 - 0.07135481 x^2)
__device__ __forceinline__ float gelu_fast(float x) {
    float x2 = x * x;
    float z = x * fmaf(-0.07135481282f, x2, -1.5957691216057308f);
    float e = __expf(z);
    return x * __builtin_amdgcn_rcpf(1.0f + e);
}

// async global->LDS, 16B per lane; LDS dest = wave-uniform base + lane*16
__device__ __forceinline__ void async16(const u16* g, u16* l) {
    __builtin_amdgcn_global_load_lds(
        (const __attribute__((address_space(1))) unsigned int*)g,
        (__attribute__((address_space(3))) unsigned int*)l, 16, 0, 0);
}

#define BAR() asm volatile("s_barrier" ::: "memory")

// ---------------------------------------------------------------------------
// Transpose-cast: src fp32 [R][C] -> dst bf16 [C][R].  Grid (C/64, R/64, Z).
// ---------------------------------------------------------------------------
__global__ __launch_bounds__(256) void tcast_kernel(const float* __restrict__ src,
                                                    u16* __restrict__ dst,
                                                    int R, int C,
                                                    size_t sstride, size_t dstride) {
    __shared__ float t[64][65];
    const float* s = src + (size_t)blockIdx.z * sstride;
    u16* d = dst + (size_t)blockIdx.z * dstride;
    int r0 = blockIdx.y * 64, c0 = blockIdx.x * 64;
    int tid = threadIdx.x;
#pragma unroll
    for (int i = 0; i < 4; i++) {
        int c = tid + i * 256;
        int row = c >> 4, col4 = (c & 15) * 4;
        float4 v = *(const float4*)(s + (size_t)(r0 + row) * C + c0 + col4);
        t[row][col4 + 0] = v.x;
        t[row][col4 + 1] = v.y;
        t[row][col4 + 2] = v.z;
        t[row][col4 + 3] = v.w;
    }
    __syncthreads();
#pragma unroll
    for (int i = 0; i < 2; i++) {
        int c = tid + i * 256;
        int dr = c >> 3, m8 = (c & 7) * 8;
        union { u16 us[8]; uint4 v; } pk;
#pragma unroll
        for (int j = 0; j < 8; j++) pk.us[j] = f2bf(t[m8 + j][dr]);
        *(uint4*)(d + (size_t)(c0 + dr) * R + r0 + m8) = pk.v;
    }
}

// ---------------------------------------------------------------------------
// bf16 transpose: src [R][C] -> dst [C][R]. Grid (C/64, R/64).
// ---------------------------------------------------------------------------
__global__ __launch_bounds__(256) void btrans_kernel(const u16* __restrict__ src,
                                                     u16* __restrict__ dst,
                                                     int R, int C) {
    __shared__ u16 t[64][72];
    int r0 = blockIdx.y * 64, c0 = blockIdx.x * 64;
    int tid = threadIdx.x;
#pragma unroll
    for (int i = 0; i < 2; i++) {
        int c = tid + i * 256;
        int row = c >> 3, s8 = (c & 7) * 8;
        *(uint4*)&t[row][s8] = *(const uint4*)(src + (size_t)(r0 + row) * C + c0 + s8);
    }
    __syncthreads();
#pragma unroll
    for (int i = 0; i < 2; i++) {
        int c = tid + i * 256;
        int row = c >> 3, s8 = (c & 7) * 8;
        union { u16 us[8]; uint4 v; } pk;
#pragma unroll
        for (int j = 0; j < 8; j++) pk.us[j] = t[s8 + j][row];
        *(uint4*)(dst + (size_t)(c0 + row) * R + r0 + s8) = pk.v;
    }
}

// ---------------------------------------------------------------------------
// LayerNorm -> bf16. One block per row, 256 threads, D=1024.
// ---------------------------------------------------------------------------
__global__ __launch_bounds__(256) void ln_kernel(const float* __restrict__ x,
                                                 const float* __restrict__ g,
                                                 const float* __restrict__ b,
                                                 u16* __restrict__ hb) {
    int row = blockIdx.x, tid = threadIdx.x;
    const float* xr = x + (size_t)row * Dc;
    float4 xv = ((const float4*)xr)[tid];
    float s = xv.x + xv.y + xv.z + xv.w;
    float ss = xv.x * xv.x + xv.y * xv.y + xv.z * xv.z + xv.w * xv.w;
    __shared__ float r1[256], r2[256];
    r1[tid] = s; r2[tid] = ss;
    __syncthreads();
    for (int off = 128; off > 0; off >>= 1) {
        if (tid < off) { r1[tid] += r1[tid + off]; r2[tid] += r2[tid + off]; }
        __syncthreads();
    }
    float mean = r1[0] * (1.0f / Dc);
    float var = r2[0] * (1.0f / Dc) - mean * mean;
    float rs = rsqrtf(var + 1e-5f);
    float4 gv = ((const float4*)g)[tid];
    float4 bv = ((const float4*)b)[tid];
    ushort4 o;
    o.x = f2bf((xv.x - mean) * rs * gv.x + bv.x);
    o.y = f2bf((xv.y - mean) * rs * gv.y + bv.y);
    o.z = f2bf((xv.z - mean) * rs * gv.z + bv.z);
    o.w = f2bf((xv.w - mean) * rs * gv.w + bv.w);
    *(ushort4*)(hb + (size_t)row * Dc + tid * 4) = o;
}

// ---------------------------------------------------------------------------
// OLD bf16 MFMA GEMM, m97 structure: kept only for MODE 1 (O-proj + residual,
// M=4096 N=1024 K=1024 -> 256 blocks of 128x128).
// ---------------------------------------------------------------------------
template <int MODE>
__global__ __launch_bounds__(256) void gemm_mfma(
    const u16* __restrict__ A, const u16* __restrict__ BT,
    int N, int K,
    u16* __restrict__ out_q, u16* __restrict__ out_k, u16* __restrict__ out_v,
    const float* __restrict__ resid, float* __restrict__ out_f32,
    u16* __restrict__ out_bf, const float* __restrict__ bias,
    const int* __restrict__ counts, const int* __restrict__ offsets,
    const int* __restrict__ list_tok) {
    const int tid = threadIdx.x;
    const int m0 = blockIdx.y * 128, n0 = blockIdx.x * 128;
    __shared__ u16 As[128][32];
    __shared__ u16 Bs[128][32];
    const u16* Bbase = BT;
    const int w = tid >> 6, lane = tid & 63;
    const int wm = (w >> 1) * 64, wn = (w & 1) * 64;
    const int lr = lane & 15, lq = lane >> 4;

    const int rA0 = w * 32 + (lane >> 2), rA1 = rA0 + 16;
    const int gsegu = (((lane & 3) ^ ((lane >> 3) & 3))) * 8;
    size_t ra0 = (size_t)(m0 + rA0) * K;
    size_t ra1 = (size_t)(m0 + rA1) * K;
    const u16* gA0 = A + ra0 + gsegu;
    const u16* gA1 = A + ra1 + gsegu;
    const u16* gB0 = Bbase + (size_t)(n0 + rA0) * K + gsegu;
    const u16* gB1 = Bbase + (size_t)(n0 + rA1) * K + gsegu;
    u16* ldsA0 = &As[w * 32][0];
    u16* ldsA1 = &As[w * 32 + 16][0];
    u16* ldsB0 = &Bs[w * 32][0];
    u16* ldsB1 = &Bs[w * 32 + 16][0];

    const int fs = (lq ^ ((lr >> 1) & 3)) * 8;
    const u16* apt[4];
    const u16* bpt[4];
#pragma unroll
    for (int i = 0; i < 4; i++) {
        apt[i] = &As[wm + i * 16 + lr][fs];
        bpt[i] = &Bs[wn + i * 16 + lr][fs];
    }

    floatx4 acc[4][4];
#pragma unroll
    for (int i = 0; i < 4; i++)
#pragma unroll
        for (int j = 0; j < 4; j++) acc[i][j] = (floatx4){0.f, 0.f, 0.f, 0.f};

    for (int k0 = 0; k0 < K; k0 += 32) {
        async16(gA0 + k0, ldsA0);
        async16(gA1 + k0, ldsA1);
        async16(gB0 + k0, ldsB0);
        async16(gB1 + k0, ldsB1);
        __syncthreads();
        short8 af[4], bfr[4];
#pragma unroll
        for (int i = 0; i < 4; i++) af[i] = *(const short8*)apt[i];
#pragma unroll
        for (int j = 0; j < 4; j++) bfr[j] = *(const short8*)bpt[j];
#pragma unroll
        for (int i = 0; i < 4; i++)
#pragma unroll
            for (int j = 0; j < 4; j++)
                acc[i][j] = __builtin_amdgcn_mfma_f32_16x16x32_bf16(af[i], bfr[j], acc[i][j], 0, 0, 0);
        __syncthreads();
    }

    // MODE 1 epilogue: + residual -> out_f32 (fp32) and out_bf (bf16)
#pragma unroll
    for (int i = 0; i < 4; i++)
#pragma unroll
        for (int j = 0; j < 4; j++) {
            int col = n0 + wn + j * 16 + lr;
            int row0 = m0 + wm + i * 16 + lq * 4;
#pragma unroll
            for (int r = 0; r < 4; r++) {
                size_t idx = (size_t)(row0 + r) * 1024 + col;
                float v = acc[i][j][r] + resid[idx];
                out_f32[idx] = v;
                out_bf[idx] = f2bf(v);
            }
        }
}

// ---------------------------------------------------------------------------
// 256x256 8-phase bf16 MFMA GEMM (m201 structure, plain HIP).
// 512 threads = 8 waves (2M x 4N), per-wave C = 128x64, BK=64.
// LDS 128KiB: 2 bufs x [A: 2 halves x 128x64][B: same], u16, XOR-swizzled
// content via pre-swizzled global source (linear global_load_lds dest).
// Counted vmcnt(6) at tile boundaries only; s_setprio around MFMA clusters.
// Epilogue (MODE 0/2): pack C into LDS, store 16B-coalesced (full 64B lines).
// MODE 0: QKV fused (N=3072, K=1024)
// MODE 2: MoE GEMM1, gathered A rows; gelu(acc+b1) -> h1 bf16 (N=4096, K=1024)
// MODE 3: MoE GEMM2, split-K=2 (z = e*2+ks); acc(+b2 if ks==0) -> h2a/h2b fp32
//         grid mapping swapped (x = m-block) so consecutive blocks share the
//         same w2T n-panel in L2.
// ---------------------------------------------------------------------------
template <int MODE>
__global__ __launch_bounds__(512, 2) void gemm256(
    const u16* __restrict__ A, const u16* __restrict__ BT, int Nn, int Kfull,
    u16* __restrict__ out_q, u16* __restrict__ out_k, u16* __restrict__ out_v,
    u16* __restrict__ out_bf, float* __restrict__ o32a, float* __restrict__ o32b,
    const float* __restrict__ bias,
    const int* __restrict__ counts, const int* __restrict__ offsets,
    const int* __restrict__ list_tok) {
    __shared__ __attribute__((aligned(16))) u16 smem[66048];  // 128KiB tiles + 1KiB toks
    int e = 0, cnt = 0, off = 0, ks = 0;
    const int bm = (MODE == 3) ? (int)blockIdx.x : (int)blockIdx.y;
    const int bn = (MODE == 3) ? (int)blockIdx.y : (int)blockIdx.x;
    if (MODE >= 2) {
        e = (MODE == 3) ? ((int)blockIdx.z >> 1) : (int)blockIdx.z;
        if (MODE == 3) ks = (int)blockIdx.z & 1;
        cnt = counts[e];
        if (bm * 256 >= cnt) return;
        off = offsets[e];
    }
    const int tid = threadIdx.x;
    const int m0 = bm * 256, n0 = bn * 256;
    const int w = tid >> 6, lane = tid & 63;
    const int wm = w >> 2, wn = w & 3;
    const int lr = lane & 15, lq = lane >> 4;
    const int sz8 = (lr & 7) << 3;  // read-side XOR swizzle (u16 units)

    int* toksL = (int*)(smem + 65536);
    if (MODE == 2) {
        if (tid < 256) toksL[tid] = list_tok[off + min(m0 + tid, cnt - 1)];
        __syncthreads();
    }
    const int K = Kfull;
    const int NT = (MODE == 3 ? 2048 : K) / 64;
    const size_t kb = (MODE == 3) ? (size_t)ks * 2048 : 0;
    const u16* Bb = BT + (MODE >= 2 ? (size_t)e * (size_t)Nn * K : (size_t)0);

    // Staging source pointers. Row r = i*64 + w*8 + (lane>>3) of the 256-row
    // tile; global k-slot pre-swizzled: sg = (lane&7)^(lane>>3) so that the
    // linear LDS write yields content readable with the sz8 XOR.
    const u16* srcA[4];
    const u16* srcB[4];
    {
        const int rl8 = w * 8 + (lane >> 3);
        const int sg = ((lane & 7) ^ (lane >> 3)) * 8;
#pragma unroll
        for (int i = 0; i < 4; i++) {
            int rA = i * 64 + rl8;
            size_t gr;
            if (MODE == 2) gr = (size_t)toksL[rA];
            else if (MODE == 3) gr = (size_t)(off + min(m0 + rA, cnt - 1));
            else gr = (size_t)(m0 + rA);
            srcA[i] = A + gr * K + kb + sg;
            srcB[i] = Bb + (size_t)(n0 + rA) * K + kb + sg;
        }
    }

    short8 areg[4][2], breg[4][2];
    floatx4 acc[8][4];
#pragma unroll
    for (int i = 0; i < 8; i++)
#pragma unroll
        for (int j = 0; j < 4; j++) acc[i][j] = (floatx4){0.f, 0.f, 0.f, 0.f};

// stage one half-tile (mat: 0=A 1=B, half h) of K-tile kt: 2 x 16B/thread
#define STG(kt, mat, h)                                                            \
    do {                                                                           \
        u16* _ld = smem + ((kt) & 1) * 32768 + (mat) * 16384 + (h) * 8192 + w * 512; \
        async16(((mat) ? srcB : srcA)[(h) * 2 + 0] + (size_t)(kt) * 64, _ld);      \
        async16(((mat) ? srcB : srcA)[(h) * 2 + 1] + (size_t)(kt) * 64, _ld + 4096); \
    } while (0)

    auto ldA = [&](int bufp, int mq) {
        const u16* ah = smem + bufp * 32768 + wm * 8192 + (mq * 64 + lr) * 64;
#pragma unroll
        for (int mf = 0; mf < 4; mf++)
#pragma unroll
            for (int kk = 0; kk < 2; kk++)
                areg[mf][kk] = *(const short8*)(ah + mf * 1024 + ((kk * 32 + lq * 8) ^ sz8));
    };
    const int bBo = 16384 + (wn >> 1) * 8192 + (wn & 1) * 4096 + lr * 64;
    auto ldB01 = [&](int bufp) {
        const u16* bh = smem + bufp * 32768 + bBo;
#pragma unroll
        for (int kk = 0; kk < 2; kk++) {
            breg[0][kk] = *(const short8*)(bh + ((kk * 32 + lq * 8) ^ sz8));
            breg[1][kk] = *(const short8*)(bh + 1024 + ((kk * 32 + lq * 8) ^ sz8));
        }
    };
    auto ldB23 = [&](int bufp) {
        const u16* bh = smem + bufp * 32768 + bBo;
#pragma unroll
        for (int kk = 0; kk < 2; kk++) {
            breg[2][kk] = *(const short8*)(bh + 2048 + ((kk * 32 + lq * 8) ^ sz8));
            breg[3][kk] = *(const short8*)(bh + 3072 + ((kk * 32 + lq * 8) ^ sz8));
        }
    };

// one C-quadrant x K=64: 16 MFMAs, setprio-wrapped. MB/NB are literals.
#define MMQ(MB, NB)                                                                  \
    do {                                                                             \
        __builtin_amdgcn_s_setprio(1);                                               \
        _Pragma("unroll") for (int kk = 0; kk < 2; kk++) {                           \
            _Pragma("unroll") for (int mi = 0; mi < 4; mi++) {                       \
                acc[(MB) + mi][(NB) + 0] = __builtin_amdgcn_mfma_f32_16x16x32_bf16(  \
                    areg[mi][kk], breg[(NB) + 0][kk], acc[(MB) + mi][(NB) + 0], 0, 0, 0); \
                acc[(MB) + mi][(NB) + 1] = __builtin_amdgcn_mfma_f32_16x16x32_bf16(  \
                    areg[mi][kk], breg[(NB) + 1][kk], acc[(MB) + mi][(NB) + 1], 0, 0, 0); \
            }                                                                        \
        }                                                                            \
        __builtin_amdgcn_s_setprio(0);                                               \
    } while (0)

    // Prologue: tile0 fully + tile1 B0,A0 (issue order matters for vmcnt math)
    STG(0, 1, 0); STG(0, 0, 0); STG(0, 0, 1); STG(0, 1, 1);
    STG(1, 1, 0); STG(1, 0, 0);

    for (int t = 0; t < NT; ++t) {
        const int bp = t & 1;
        // ---- phase 0: stage (t+1).A1; vmcnt guarantees tile t landed ----
        if (t + 1 < NT) STG(t + 1, 0, 1);
        if (t == NT - 1) { asm volatile("s_waitcnt vmcnt(0)" ::: "memory"); }
        else             { asm volatile("s_waitcnt vmcnt(6)" ::: "memory"); }
        BAR();
        ldA(bp, 0);
        ldB01(bp);
        MMQ(0, 0);
        BAR();
        // ---- phase 1 ----
        ldB23(bp);
        if (t + 1 < NT) STG(t + 1, 1, 1);
        BAR();
        MMQ(0, 2);
        BAR();
        // ---- phase 2 ----
        ldA(bp, 1);
        if (t + 2 < NT) STG(t + 2, 1, 0);
        BAR();
        MMQ(4, 0);
        BAR();
        // ---- phase 3 ----
        if (t + 2 < NT) STG(t + 2, 0, 0);
        BAR();
        MMQ(4, 2);
        BAR();
    }
#undef STG
#undef MMQ

    // Epilogue. C/D layout: col = lane&15 (=lr), row = lq*4 + reg.
    if (MODE == 0 || MODE == 2) {
        // Pack C tile into LDS (bijective 16B-group XOR swizzle keyed on row&7),
        // then store with 512 threads x 16B fully-contiguous chunks.
#pragma unroll
        for (int nj = 0; nj < 4; nj++) {
            const int colg = wn * 64 + nj * 16 + lr;
            const float bv = (MODE == 2) ? bias[(size_t)e * 4096 + n0 + colg] : 0.f;
            const int g = colg >> 3, rem = colg & 7;
#pragma unroll
            for (int fi = 0; fi < 8; fi++) {
#pragma unroll
                for (int r = 0; r < 4; r++) {
                    const int row = wm * 128 + fi * 16 + lq * 4 + r;
                    float v = acc[fi][nj][r];
                    if (MODE == 2) v = gelu_fast(v + bv);
                    const int pg = (g & ~7) | ((g ^ row) & 7);
                    smem[row * 256 + pg * 8 + rem] = f2bf(v);
                }
            }
        }
        __syncthreads();
        const int mat = n0 >> 10;
        u16* dst0 = (MODE == 0) ? ((mat == 0) ? out_q : (mat == 1 ? out_k : out_v)) : out_bf;
#pragma unroll
        for (int p = 0; p < 16; p++) {
            const int f = tid + p * 512;
            const int row = f >> 5, g = f & 31;
            const int pg = (g & ~7) | ((g ^ row) & 7);
            const uint4 val = *(const uint4*)&smem[row * 256 + pg * 8];
            if (MODE == 0) {
                const int cc = (n0 + g * 8) & 1023;
                *(uint4*)&dst0[(size_t)(m0 + row) * 1024 + cc] = val;
            } else {
                if (m0 + row < cnt)
                    *(uint4*)&dst0[(size_t)(off + m0 + row) * 4096 + n0 + g * 8] = val;
            }
        }
    } else if (MODE == 3) {
        float* o = ks ? o32b : o32a;
#pragma unroll
        for (int nj = 0; nj < 4; nj++) {
            const int col = n0 + wn * 64 + nj * 16 + lr;
            const float bv = ks ? 0.f : bias[(size_t)e * 1024 + col];
#pragma unroll
            for (int fi = 0; fi < 8; fi++) {
                const int rl0 = m0 + wm * 128 + fi * 16 + lq * 4;
#pragma unroll
                for (int r = 0; r < 4; r++)
                    if (rl0 + r < cnt)
                        o[(size_t)(off + rl0 + r) * 1024 + col] = acc[fi][nj][r] + bv;
            }
        }
    }
}

// ---------------------------------------------------------------------------
// Flash attention, bf16 MFMA. Grid (S/64, H, B), 256 threads = 4 waves.
// Output packed through ps (LDS) for full-line coalesced stores.
// ---------------------------------------------------------------------------
__global__ __launch_bounds__(256) void attn_mfma(const u16* __restrict__ qb,
                                                 const u16* __restrict__ kb,
                                                 const u16* __restrict__ vt,
                                                 u16* __restrict__ aob) {
    __shared__ u16 qs[64][72], ks[64][72], vs[64][72], ps[64][72];
    const int q0 = blockIdx.x * 64, h = blockIdx.y, b = blockIdx.z;
    const int tid = threadIdx.x, w = tid >> 6, lane = tid & 63;
    const int lr = lane & 15, lq = lane >> 4;
    const int ms = w * 16;
    const size_t tok0 = (size_t)b * Sc;

#pragma unroll
    for (int i = 0; i < 2; i++) {
        int c = tid + i * 256;
        int row = c >> 3, d8 = (c & 7) * 8;
        *(uint4*)&qs[row][d8] = *(const uint4*)(qb + (tok0 + q0 + row) * 1024 + h * 64 + d8);
    }
    __syncthreads();
    short8 qa[2];
    qa[0] = *(const short8*)&qs[ms + lr][lq * 8];
    qa[1] = *(const short8*)&qs[ms + lr][32 + lq * 8];

    floatx4 oacc[4];
    float m_r[4], l_r[4];
#pragma unroll
    for (int d4 = 0; d4 < 4; d4++) oacc[d4] = (floatx4){0.f, 0.f, 0.f, 0.f};
#pragma unroll
    for (int r = 0; r < 4; r++) { m_r[r] = -1e30f; l_r[r] = 0.f; }

    for (int kt = 0; kt < Sc / 64; kt++) {
        int k0 = kt * 64;
        __syncthreads();
#pragma unroll
        for (int i = 0; i < 2; i++) {
            int c = tid + i * 256;
            int row = c >> 3, d8 = (c & 7) * 8;
            *(uint4*)&ks[row][d8] = *(const uint4*)(kb + (tok0 + k0 + row) * 1024 + h * 64 + d8);
            *(uint4*)&vs[row][d8] = *(const uint4*)(vt + (size_t)(h * 64 + row) * 4096 + tok0 + k0 + d8);
        }
        __syncthreads();
        floatx4 sfr[4];
#pragma unroll
        for (int j4 = 0; j4 < 4; j4++) {
            short8 kf0 = *(const short8*)&ks[j4 * 16 + lr][lq * 8];
            short8 kf1 = *(const short8*)&ks[j4 * 16 + lr][32 + lq * 8];
            floatx4 sa = (floatx4){0.f, 0.f, 0.f, 0.f};
            sa = __builtin_amdgcn_mfma_f32_16x16x32_bf16(qa[0], kf0, sa, 0, 0, 0);
            sa = __builtin_amdgcn_mfma_f32_16x16x32_bf16(qa[1], kf1, sa, 0, 0, 0);
            sfr[j4] = sa * 0.125f;
        }
#pragma unroll
        for (int r = 0; r < 4; r++) {
            float mx = fmaxf(fmaxf(sfr[0][r], sfr[1][r]), fmaxf(sfr[2][r], sfr[3][r]));
            mx = fmaxf(mx, __shfl_xor(mx, 1, 64));
            mx = fmaxf(mx, __shfl_xor(mx, 2, 64));
            mx = fmaxf(mx, __shfl_xor(mx, 4, 64));
            mx = fmaxf(mx, __shfl_xor(mx, 8, 64));
            float mn = fmaxf(m_r[r], mx);
            float alpha = __expf(m_r[r] - mn);
            m_r[r] = mn;
            float rs = 0.f;
#pragma unroll
            for (int j4 = 0; j4 < 4; j4++) {
                float p = __expf(sfr[j4][r] - mn);
                sfr[j4][r] = p;
                rs += p;
            }
            rs += __shfl_xor(rs, 1, 64);
            rs += __shfl_xor(rs, 2, 64);
            rs += __shfl_xor(rs, 4, 64);
            rs += __shfl_xor(rs, 8, 64);
            l_r[r] = l_r[r] * alpha + rs;
#pragma unroll
            for (int d4 = 0; d4 < 4; d4++) oacc[d4][r] *= alpha;
        }
#pragma unroll
        for (int j4 = 0; j4 < 4; j4++)
#pragma unroll
            for (int r = 0; r < 4; r++)
                ps[ms + lq * 4 + r][j4 * 16 + lr] = f2bf(sfr[j4][r]);
        __syncthreads();
        short8 pa0 = *(const short8*)&ps[ms + lr][lq * 8];
        short8 pa1 = *(const short8*)&ps[ms + lr][32 + lq * 8];
#pragma unroll
        for (int d4 = 0; d4 < 4; d4++) {
            short8 vf0 = *(const short8*)&vs[d4 * 16 + lr][lq * 8];
            short8 vf1 = *(const short8*)&vs[d4 * 16 + lr][32 + lq * 8];
            oacc[d4] = __builtin_amdgcn_mfma_f32_16x16x32_bf16(pa0, vf0, oacc[d4], 0, 0, 0);
            oacc[d4] = __builtin_amdgcn_mfma_f32_16x16x32_bf16(pa1, vf1, oacc[d4], 0, 0, 0);
        }
    }
    // Pack O through ps (each wave writes only its own 16 rows), then store
    // 16B-contiguous chunks: 8 lanes cover one row's 128B => full 64B lines.
#pragma unroll
    for (int r = 0; r < 4; r++) {
        float inv = 1.0f / l_r[r];
#pragma unroll
        for (int d4 = 0; d4 < 4; d4++)
            ps[ms + lq * 4 + r][d4 * 16 + lr] = f2bf(oacc[d4][r] * inv);
    }
    __syncthreads();
#pragma unroll
    for (int p = 0; p < 2; p++) {
        int f = tid + p * 256;
        int row = f >> 3, g = f & 7;
        uint4 v = *(const uint4*)&ps[row][g * 8];
        *(uint4*)&aob[(tok0 + q0 + row) * 1024 + h * 64 + g * 8] = v;
    }
}

// ---------------------------------------------------------------------------
// Router, scan, scatter, combine
// ---------------------------------------------------------------------------
__global__ __launch_bounds__(256) void router_kernel(const float* __restrict__ x2,
                                                     const float* __restrict__ Wg,
                                                     int* __restrict__ topi,
                                                     float* __restrict__ topw,
                                                     int* __restrict__ counts) {
    int t = blockIdx.x, tid = threadIdx.x;
    float p[Ec] = {};
    const float* xr = x2 + (size_t)t * Dc;
    for (int k = tid; k < Dc; k += 256) {
        float xv = xr[k];
        const float* wr = Wg + (size_t)k * Ec;
#pragma unroll
        for (int e = 0; e < Ec; e++) p[e] += xv * wr[e];
    }
    __shared__ float red[256 * Ec];
#pragma unroll
    for (int e = 0; e < Ec; e++) red[tid * Ec + e] = p[e];
    __syncthreads();
    for (int off = 128; off > 0; off >>= 1) {
        if (tid < off) {
#pragma unroll
            for (int e = 0; e < Ec; e++) red[tid * Ec + e] += red[(tid + off) * Ec + e];
        }
        __syncthreads();
    }
    if (tid == 0) {
        float l[Ec];
        float mx = -1e30f;
#pragma unroll
        for (int e = 0; e < Ec; e++) { l[e] = red[e]; mx = fmaxf(mx, l[e]); }
#pragma unroll
        for (int e = 0; e < Ec; e++) l[e] = __expf(l[e] - mx);
        int i0 = 0;
#pragma unroll
        for (int e = 1; e < Ec; e++) if (l[e] > l[i0]) i0 = e;
        int i1 = (i0 == 0) ? 1 : 0;
#pragma unroll
        for (int e = 0; e < Ec; e++) if (e != i0 && l[e] > l[i1]) i1 = e;
        float v0 = l[i0], v1 = l[i1];
        float inv = 1.0f / (v0 + v1);
        topi[t * 2 + 0] = i0;
        topi[t * 2 + 1] = i1;
        topw[t * 2 + 0] = v0 * inv;
        topw[t * 2 + 1] = v1 * inv;
        atomicAdd(&counts[i0], 1);
        atomicAdd(&counts[i1], 1);
    }
}

__global__ void zero_small(int* counts, int* cursor) {
    int i = threadIdx.x;
    if (i < Ec) { counts[i] = 0; cursor[i] = 0; }
}

__global__ void scan_kernel(const int* counts, int* offsets) {
    if (threadIdx.x == 0) {
        int s = 0;
        for (int e = 0; e < Ec; e++) { offsets[e] = s; s += counts[e]; }
    }
}

__global__ __launch_bounds__(256) void scatter_kernel(const int* __restrict__ topi,
                                                      const int* __restrict__ offsets,
                                                      int* __restrict__ cursor,
                                                      int* __restrict__ list_tok,
                                                      int* __restrict__ slot_of) {
    int t = blockIdx.x * 256 + threadIdx.x;
    if (t >= NTOK) return;
    for (int s2 = 0; s2 < 2; s2++) {
        int e = topi[t * 2 + s2];
        int p = offsets[e] + atomicAdd(&cursor[e], 1);
        list_tok[p] = t;
        slot_of[t * 2 + s2] = p;
    }
}

__global__ __launch_bounds__(256) void combine_kernel(const float* __restrict__ x2,
                                                      const float* __restrict__ h2a,
                                                      const float* __restrict__ h2b,
                                                      const int* __restrict__ slot_of,
                                                      const float* __restrict__ topw,
                                                      float* __restrict__ out) {
    int t = blockIdx.x, c = threadIdx.x;
    int s0 = slot_of[t * 2], s1 = slot_of[t * 2 + 1];
    float w0 = topw[t * 2], w1 = topw[t * 2 + 1];
    float4 a = ((const float4*)(x2 + (size_t)t * Dc))[c];
    float4 p0 = ((const float4*)(h2a + (size_t)s0 * Dc))[c];
    float4 q0 = ((const float4*)(h2b + (size_t)s0 * Dc))[c];
    float4 p1 = ((const float4*)(h2a + (size_t)s1 * Dc))[c];
    float4 q1 = ((const float4*)(h2b + (size_t)s1 * Dc))[c];
    float4 o;
    o.x = a.x + w0 * (p0.x + q0.x) + w1 * (p1.x + q1.x);
    o.y = a.y + w0 * (p0.y + q0.y) + w1 * (p1.y + q1.y);
    o.z = a.z + w0 * (p0.z + q0.z) + w1 * (p1.z + q1.z);
    o.w = a.w + w0 * (p0.w + q0.w) + w1 * (p1.w + q1.w);
    ((float4*)(out + (size_t)t * Dc))[c] = o;
}

// ---------------------------------------------------------------------------
// Workspace (MB):
//  [0,16) x2 fp32   [16,24) x2b    [24,32) hb
//  [32,38) wqkvT    [38,40) woT
//  [40,48) qb  [48,56) kb  [56,64) vt  [64,72) vb->aob   (reused as h2b later)
//  [72,136) w1T     [136,200) w2T  [200,264) h1  [264,296) h2a
//  [296..) router scratch
// ---------------------------------------------------------------------------
extern "C" void kernel_launch(void* const* d_in, const int* in_sizes, int n_in,
                              void* d_out, int out_size, void* d_ws, size_t ws_size,
                              hipStream_t stream) {
    const float* x    = (const float*)d_in[0];
    const float* ln_g = (const float*)d_in[1];
    const float* ln_b = (const float*)d_in[2];
    const float* Wq   = (const float*)d_in[3];
    const float* Wk   = (const float*)d_in[4];
    const float* Wv   = (const float*)d_in[5];
    const float* Wo   = (const float*)d_in[6];
    const float* Wg   = (const float*)d_in[7];
    const float* W1   = (const float*)d_in[8];
    const float* b1   = (const float*)d_in[9];
    const float* W2   = (const float*)d_in[10];
    const float* b2   = (const float*)d_in[11];
    float* out = (float*)d_out;

    char* ws = (char*)d_ws;
    const size_t MB = 1ull << 20;
    float* x2    = (float*)(ws + 0 * MB);
    u16* x2b     = (u16*)(ws + 16 * MB);
    u16* hb      = (u16*)(ws + 24 * MB);
    u16* wqkvT   = (u16*)(ws + 32 * MB);
    u16* woT     = (u16*)(ws + 38 * MB);
    u16* qb      = (u16*)(ws + 40 * MB);
    u16* kb      = (u16*)(ws + 48 * MB);
    u16* vt      = (u16*)(ws + 56 * MB);
    u16* vb      = (u16*)(ws + 64 * MB);  // dead after btrans; reused as aob
    u16* aob     = (u16*)(ws + 64 * MB);
    float* h2b   = (float*)(ws + 40 * MB);  // reuses qb/kb/vt/aob (dead post-attn)
    u16* w1T     = (u16*)(ws + 72 * MB);
    u16* w2T     = (u16*)(ws + 136 * MB);
    u16* h1      = (u16*)(ws + 200 * MB);
    float* h2    = (float*)(ws + 264 * MB);
    char* sm     = ws + 296 * MB;
    float* topw    = (float*)(sm);
    int*   topi    = (int*)(sm + (1 << 15));
    int*   slot_of = (int*)(sm + 2 * (1 << 15));
    int*   list_tok= (int*)(sm + 3 * (1 << 15));
    int*   counts  = (int*)(sm + 4 * (1 << 15));
    int*   offsets = counts + 64;
    int*   cursor  = counts + 128;

    // weight transpose-casts
    tcast_kernel<<<dim3(16, 16, 1), 256, 0, stream>>>(Wq, wqkvT + 0 * 1024 * 1024, 1024, 1024, 0, 0);
    tcast_kernel<<<dim3(16, 16, 1), 256, 0, stream>>>(Wk, wqkvT + 1 * 1024 * 1024, 1024, 1024, 0, 0);
    tcast_kernel<<<dim3(16, 16, 1), 256, 0, stream>>>(Wv, wqkvT + 2 * 1024 * 1024, 1024, 1024, 0, 0);
    tcast_kernel<<<dim3(16, 16, 1), 256, 0, stream>>>(Wo, woT, 1024, 1024, 0, 0);
    tcast_kernel<<<dim3(64, 16, 8), 256, 0, stream>>>(W1, w1T, 1024, 4096,
                                                      (size_t)1024 * 4096, (size_t)4096 * 1024);
    tcast_kernel<<<dim3(16, 64, 8), 256, 0, stream>>>(W2, w2T, 4096, 1024,
                                                      (size_t)4096 * 1024, (size_t)1024 * 4096);

    // attention
    ln_kernel<<<NTOK, 256, 0, stream>>>(x, ln_g, ln_b, hb);
    gemm256<0><<<dim3(12, 16, 1), 512, 0, stream>>>(hb, wqkvT, 3072, 1024,
                                                    qb, kb, vb, nullptr, nullptr, nullptr,
                                                    nullptr, nullptr, nullptr, nullptr);
    btrans_kernel<<<dim3(16, 64), 256, 0, stream>>>(vb, vt, 4096, 1024);
    attn_mfma<<<dim3(Sc / 64, 16, 2), 256, 0, stream>>>(qb, kb, vt, aob);
    gemm_mfma<1><<<dim3(8, 32), 256, 0, stream>>>(aob, woT, 1024, 1024,
                                                  nullptr, nullptr, nullptr, x, x2, x2b, nullptr,
                                                  nullptr, nullptr, nullptr);

    // routing
    zero_small<<<1, 64, 0, stream>>>(counts, cursor);
    router_kernel<<<NTOK, 256, 0, stream>>>(x2, Wg, topi, topw, counts);
    scan_kernel<<<1, 1, 0, stream>>>(counts, offsets);
    scatter_kernel<<<NTOK / 256, 256, 0, stream>>>(topi, offsets, cursor, list_tok, slot_of);

    // experts
    gemm256<2><<<dim3(16, 16, 8), 512, 0, stream>>>(x2b, w1T, 4096, 1024,
                                                    nullptr, nullptr, nullptr,
                                                    h1, nullptr, nullptr, b1,
                                                    counts, offsets, list_tok);
    gemm256<3><<<dim3(16, 4, 16), 512, 0, stream>>>(h1, w2T, 1024, 4096,
                                                    nullptr, nullptr, nullptr,
                                                    nullptr, h2, h2b, b2,
                                                    counts, offsets, list_tok);
    combine_kernel<<<NTOK, 256, 0, stream>>>(x2, h2, h2b, slot_of, topw, out);
}

// Round 3
// 949.768 us; speedup vs baseline: 1.1278x; 1.1278x over previous
//
#include <hip/hip_runtime.h>
#include <hip/hip_bf16.h>

// AGIFORMERBlock: B=2, S=2048, D=1024, H=16 (dh=64), F=4096, E=8, K=2
constexpr int Sc = 2048;
constexpr int Dc = 1024;
constexpr int Fc = 4096;
constexpr int Ec = 8;
constexpr int NTOK = 4096;  // B*S

typedef __attribute__((ext_vector_type(8))) short short8;
typedef __attribute__((ext_vector_type(4))) float floatx4;
typedef unsigned short u16;

__device__ __forceinline__ u16 f2bf(float f) {
    __hip_bfloat16 h = __float2bfloat16(f);
    return *reinterpret_cast<u16*>(&h);
}

// tanh-gelu via sigmoid identity: 0.5x(1+tanh(y)) = x * 1/(1+exp(-2y)),
// y = 0.79788456(x + 0.044715 x^3)  ->  -2y = x*(-1.59576912 - 0.07135481 x^2)
__device__ __forceinline__ float gelu_fast(float x) {
    float x2 = x * x;
    float z = x * fmaf(-0.07135481282f, x2, -1.5957691216057308f);
    float e = __expf(z);
    return x * __builtin_amdgcn_rcpf(1.0f + e);
}

// async global->LDS, 16B per lane; LDS dest = wave-uniform base + lane*16
__device__ __forceinline__ void async16(const u16* g, u16* l) {
    __builtin_amdgcn_global_load_lds(
        (const __attribute__((address_space(1))) unsigned int*)g,
        (__attribute__((address_space(3))) unsigned int*)l, 16, 0, 0);
}

#define BAR() asm volatile("s_barrier" ::: "memory")

// ---------------------------------------------------------------------------
// Transpose-cast: src fp32 [R][C] -> dst bf16 [C][R].  Grid (C/64, R/64, Z).
// ---------------------------------------------------------------------------
__global__ __launch_bounds__(256) void tcast_kernel(const float* __restrict__ src,
                                                    u16* __restrict__ dst,
                                                    int R, int C,
                                                    size_t sstride, size_t dstride) {
    __shared__ float t[64][65];
    const float* s = src + (size_t)blockIdx.z * sstride;
    u16* d = dst + (size_t)blockIdx.z * dstride;
    int r0 = blockIdx.y * 64, c0 = blockIdx.x * 64;
    int tid = threadIdx.x;
#pragma unroll
    for (int i = 0; i < 4; i++) {
        int c = tid + i * 256;
        int row = c >> 4, col4 = (c & 15) * 4;
        float4 v = *(const float4*)(s + (size_t)(r0 + row) * C + c0 + col4);
        t[row][col4 + 0] = v.x;
        t[row][col4 + 1] = v.y;
        t[row][col4 + 2] = v.z;
        t[row][col4 + 3] = v.w;
    }
    __syncthreads();
#pragma unroll
    for (int i = 0; i < 2; i++) {
        int c = tid + i * 256;
        int dr = c >> 3, m8 = (c & 7) * 8;
        union { u16 us[8]; uint4 v; } pk;
#pragma unroll
        for (int j = 0; j < 8; j++) pk.us[j] = f2bf(t[m8 + j][dr]);
        *(uint4*)(d + (size_t)(c0 + dr) * R + r0 + m8) = pk.v;
    }
}

// ---------------------------------------------------------------------------
// bf16 transpose: src [R][C] -> dst [C][R]. Grid (C/64, R/64).
// ---------------------------------------------------------------------------
__global__ __launch_bounds__(256) void btrans_kernel(const u16* __restrict__ src,
                                                     u16* __restrict__ dst,
                                                     int R, int C) {
    __shared__ u16 t[64][72];
    int r0 = blockIdx.y * 64, c0 = blockIdx.x * 64;
    int tid = threadIdx.x;
#pragma unroll
    for (int i = 0; i < 2; i++) {
        int c = tid + i * 256;
        int row = c >> 3, s8 = (c & 7) * 8;
        *(uint4*)&t[row][s8] = *(const uint4*)(src + (size_t)(r0 + row) * C + c0 + s8);
    }
    __syncthreads();
#pragma unroll
    for (int i = 0; i < 2; i++) {
        int c = tid + i * 256;
        int row = c >> 3, s8 = (c & 7) * 8;
        union { u16 us[8]; uint4 v; } pk;
#pragma unroll
        for (int j = 0; j < 8; j++) pk.us[j] = t[s8 + j][row];
        *(uint4*)(dst + (size_t)(c0 + row) * R + r0 + s8) = pk.v;
    }
}

// ---------------------------------------------------------------------------
// LayerNorm -> bf16. One block per row, 256 threads, D=1024.
// ---------------------------------------------------------------------------
__global__ __launch_bounds__(256) void ln_kernel(const float* __restrict__ x,
                                                 const float* __restrict__ g,
                                                 const float* __restrict__ b,
                                                 u16* __restrict__ hb) {
    int row = blockIdx.x, tid = threadIdx.x;
    const float* xr = x + (size_t)row * Dc;
    float4 xv = ((const float4*)xr)[tid];
    float s = xv.x + xv.y + xv.z + xv.w;
    float ss = xv.x * xv.x + xv.y * xv.y + xv.z * xv.z + xv.w * xv.w;
    __shared__ float r1[256], r2[256];
    r1[tid] = s; r2[tid] = ss;
    __syncthreads();
    for (int off = 128; off > 0; off >>= 1) {
        if (tid < off) { r1[tid] += r1[tid + off]; r2[tid] += r2[tid + off]; }
        __syncthreads();
    }
    float mean = r1[0] * (1.0f / Dc);
    float var = r2[0] * (1.0f / Dc) - mean * mean;
    float rs = rsqrtf(var + 1e-5f);
    float4 gv = ((const float4*)g)[tid];
    float4 bv = ((const float4*)b)[tid];
    ushort4 o;
    o.x = f2bf((xv.x - mean) * rs * gv.x + bv.x);
    o.y = f2bf((xv.y - mean) * rs * gv.y + bv.y);
    o.z = f2bf((xv.z - mean) * rs * gv.z + bv.z);
    o.w = f2bf((xv.w - mean) * rs * gv.w + bv.w);
    *(ushort4*)(hb + (size_t)row * Dc + tid * 4) = o;
}

// ---------------------------------------------------------------------------
// OLD bf16 MFMA GEMM, m97 structure: kept only for MODE 1 (O-proj + residual,
// M=4096 N=1024 K=1024 -> 256 blocks of 128x128).
// ---------------------------------------------------------------------------
template <int MODE>
__global__ __launch_bounds__(256) void gemm_mfma(
    const u16* __restrict__ A, const u16* __restrict__ BT,
    int N, int K,
    u16* __restrict__ out_q, u16* __restrict__ out_k, u16* __restrict__ out_v,
    const float* __restrict__ resid, float* __restrict__ out_f32,
    u16* __restrict__ out_bf, const float* __restrict__ bias,
    const int* __restrict__ counts, const int* __restrict__ offsets,
    const int* __restrict__ list_tok) {
    const int tid = threadIdx.x;
    const int m0 = blockIdx.y * 128, n0 = blockIdx.x * 128;
    __shared__ u16 As[128][32];
    __shared__ u16 Bs[128][32];
    const u16* Bbase = BT;
    const int w = tid >> 6, lane = tid & 63;
    const int wm = (w >> 1) * 64, wn = (w & 1) * 64;
    const int lr = lane & 15, lq = lane >> 4;

    const int rA0 = w * 32 + (lane >> 2), rA1 = rA0 + 16;
    const int gsegu = (((lane & 3) ^ ((lane >> 3) & 3))) * 8;
    size_t ra0 = (size_t)(m0 + rA0) * K;
    size_t ra1 = (size_t)(m0 + rA1) * K;
    const u16* gA0 = A + ra0 + gsegu;
    const u16* gA1 = A + ra1 + gsegu;
    const u16* gB0 = Bbase + (size_t)(n0 + rA0) * K + gsegu;
    const u16* gB1 = Bbase + (size_t)(n0 + rA1) * K + gsegu;
    u16* ldsA0 = &As[w * 32][0];
    u16* ldsA1 = &As[w * 32 + 16][0];
    u16* ldsB0 = &Bs[w * 32][0];
    u16* ldsB1 = &Bs[w * 32 + 16][0];

    const int fs = (lq ^ ((lr >> 1) & 3)) * 8;
    const u16* apt[4];
    const u16* bpt[4];
#pragma unroll
    for (int i = 0; i < 4; i++) {
        apt[i] = &As[wm + i * 16 + lr][fs];
        bpt[i] = &Bs[wn + i * 16 + lr][fs];
    }

    floatx4 acc[4][4];
#pragma unroll
    for (int i = 0; i < 4; i++)
#pragma unroll
        for (int j = 0; j < 4; j++) acc[i][j] = (floatx4){0.f, 0.f, 0.f, 0.f};

    for (int k0 = 0; k0 < K; k0 += 32) {
        async16(gA0 + k0, ldsA0);
        async16(gA1 + k0, ldsA1);
        async16(gB0 + k0, ldsB0);
        async16(gB1 + k0, ldsB1);
        __syncthreads();
        short8 af[4], bfr[4];
#pragma unroll
        for (int i = 0; i < 4; i++) af[i] = *(const short8*)apt[i];
#pragma unroll
        for (int j = 0; j < 4; j++) bfr[j] = *(const short8*)bpt[j];
#pragma unroll
        for (int i = 0; i < 4; i++)
#pragma unroll
            for (int j = 0; j < 4; j++)
                acc[i][j] = __builtin_amdgcn_mfma_f32_16x16x32_bf16(af[i], bfr[j], acc[i][j], 0, 0, 0);
        __syncthreads();
    }

    // MODE 1 epilogue: + residual -> out_f32 (fp32) and out_bf (bf16)
#pragma unroll
    for (int i = 0; i < 4; i++)
#pragma unroll
        for (int j = 0; j < 4; j++) {
            int col = n0 + wn + j * 16 + lr;
            int row0 = m0 + wm + i * 16 + lq * 4;
#pragma unroll
            for (int r = 0; r < 4; r++) {
                size_t idx = (size_t)(row0 + r) * 1024 + col;
                float v = acc[i][j][r] + resid[idx];
                out_f32[idx] = v;
                out_bf[idx] = f2bf(v);
            }
        }
}

// ---------------------------------------------------------------------------
// 256x256 8-phase bf16 MFMA GEMM (m201 structure, plain HIP).
// 512 threads = 8 waves (2M x 4N), per-wave C = 128x64, BK=64.
// LDS 128KiB: 2 bufs x [A: 2 halves x 128x64][B: same], u16, XOR-swizzled
// content via pre-swizzled global source (linear global_load_lds dest).
// Counted vmcnt(6) at tile boundaries only; s_setprio around MFMA clusters.
// Epilogue (MODE 0/2): pack C into LDS, store 16B-coalesced (full 64B lines).
// MODE 0: QKV fused (N=3072, K=1024)
// MODE 2: MoE GEMM1, gathered A rows; gelu(acc+b1) -> h1 bf16 (N=4096, K=1024)
// MODE 3: MoE GEMM2, split-K=2 (z = e*2+ks); acc(+b2 if ks==0) -> h2a/h2b fp32
// Grid mapping: x = n-block ALWAYS. (R2 post-mortem: putting the m-block on x
// with mostly-null m-blocks made useful linear IDs = {0..3} mod 16, and the
// round-robin id%8 XCD assignment starved XCDs 4-7 -> occupancy 17%->6%,
// MODE3 145->277us. Useful-block stride must not be = 0 mod 8.)
// ---------------------------------------------------------------------------
template <int MODE>
__global__ __launch_bounds__(512, 2) void gemm256(
    const u16* __restrict__ A, const u16* __restrict__ BT, int Nn, int Kfull,
    u16* __restrict__ out_q, u16* __restrict__ out_k, u16* __restrict__ out_v,
    u16* __restrict__ out_bf, float* __restrict__ o32a, float* __restrict__ o32b,
    const float* __restrict__ bias,
    const int* __restrict__ counts, const int* __restrict__ offsets,
    const int* __restrict__ list_tok) {
    __shared__ __attribute__((aligned(16))) u16 smem[66048];  // 128KiB tiles + 1KiB toks
    int e = 0, cnt = 0, off = 0, ks = 0;
    const int bm = (int)blockIdx.y;
    const int bn = (int)blockIdx.x;
    if (MODE >= 2) {
        e = (MODE == 3) ? ((int)blockIdx.z >> 1) : (int)blockIdx.z;
        if (MODE == 3) ks = (int)blockIdx.z & 1;
        cnt = counts[e];
        if (bm * 256 >= cnt) return;
        off = offsets[e];
    }
    const int tid = threadIdx.x;
    const int m0 = bm * 256, n0 = bn * 256;
    const int w = tid >> 6, lane = tid & 63;
    const int wm = w >> 2, wn = w & 3;
    const int lr = lane & 15, lq = lane >> 4;
    const int sz8 = (lr & 7) << 3;  // read-side XOR swizzle (u16 units)

    int* toksL = (int*)(smem + 65536);
    if (MODE == 2) {
        if (tid < 256) toksL[tid] = list_tok[off + min(m0 + tid, cnt - 1)];
        __syncthreads();
    }
    const int K = Kfull;
    const int NT = (MODE == 3 ? 2048 : K) / 64;
    const size_t kb = (MODE == 3) ? (size_t)ks * 2048 : 0;
    const u16* Bb = BT + (MODE >= 2 ? (size_t)e * (size_t)Nn * K : (size_t)0);

    // Staging source pointers. Row r = i*64 + w*8 + (lane>>3) of the 256-row
    // tile; global k-slot pre-swizzled: sg = (lane&7)^(lane>>3) so that the
    // linear LDS write yields content readable with the sz8 XOR.
    const u16* srcA[4];
    const u16* srcB[4];
    {
        const int rl8 = w * 8 + (lane >> 3);
        const int sg = ((lane & 7) ^ (lane >> 3)) * 8;
#pragma unroll
        for (int i = 0; i < 4; i++) {
            int rA = i * 64 + rl8;
            size_t gr;
            if (MODE == 2) gr = (size_t)toksL[rA];
            else if (MODE == 3) gr = (size_t)(off + min(m0 + rA, cnt - 1));
            else gr = (size_t)(m0 + rA);
            srcA[i] = A + gr * K + kb + sg;
            srcB[i] = Bb + (size_t)(n0 + rA) * K + kb + sg;
        }
    }

    short8 areg[4][2], breg[4][2];
    floatx4 acc[8][4];
#pragma unroll
    for (int i = 0; i < 8; i++)
#pragma unroll
        for (int j = 0; j < 4; j++) acc[i][j] = (floatx4){0.f, 0.f, 0.f, 0.f};

// stage one half-tile (mat: 0=A 1=B, half h) of K-tile kt: 2 x 16B/thread
#define STG(kt, mat, h)                                                            \
    do {                                                                           \
        u16* _ld = smem + ((kt) & 1) * 32768 + (mat) * 16384 + (h) * 8192 + w * 512; \
        async16(((mat) ? srcB : srcA)[(h) * 2 + 0] + (size_t)(kt) * 64, _ld);      \
        async16(((mat) ? srcB : srcA)[(h) * 2 + 1] + (size_t)(kt) * 64, _ld + 4096); \
    } while (0)

    auto ldA = [&](int bufp, int mq) {
        const u16* ah = smem + bufp * 32768 + wm * 8192 + (mq * 64 + lr) * 64;
#pragma unroll
        for (int mf = 0; mf < 4; mf++)
#pragma unroll
            for (int kk = 0; kk < 2; kk++)
                areg[mf][kk] = *(const short8*)(ah + mf * 1024 + ((kk * 32 + lq * 8) ^ sz8));
    };
    const int bBo = 16384 + (wn >> 1) * 8192 + (wn & 1) * 4096 + lr * 64;
    auto ldB01 = [&](int bufp) {
        const u16* bh = smem + bufp * 32768 + bBo;
#pragma unroll
        for (int kk = 0; kk < 2; kk++) {
            breg[0][kk] = *(const short8*)(bh + ((kk * 32 + lq * 8) ^ sz8));
            breg[1][kk] = *(const short8*)(bh + 1024 + ((kk * 32 + lq * 8) ^ sz8));
        }
    };
    auto ldB23 = [&](int bufp) {
        const u16* bh = smem + bufp * 32768 + bBo;
#pragma unroll
        for (int kk = 0; kk < 2; kk++) {
            breg[2][kk] = *(const short8*)(bh + 2048 + ((kk * 32 + lq * 8) ^ sz8));
            breg[3][kk] = *(const short8*)(bh + 3072 + ((kk * 32 + lq * 8) ^ sz8));
        }
    };

// one C-quadrant x K=64: 16 MFMAs, setprio-wrapped. MB/NB are literals.
#define MMQ(MB, NB)                                                                  \
    do {                                                                             \
        __builtin_amdgcn_s_setprio(1);                                               \
        _Pragma("unroll") for (int kk = 0; kk < 2; kk++) {                           \
            _Pragma("unroll") for (int mi = 0; mi < 4; mi++) {                       \
                acc[(MB) + mi][(NB) + 0] = __builtin_amdgcn_mfma_f32_16x16x32_bf16(  \
                    areg[mi][kk], breg[(NB) + 0][kk], acc[(MB) + mi][(NB) + 0], 0, 0, 0); \
                acc[(MB) + mi][(NB) + 1] = __builtin_amdgcn_mfma_f32_16x16x32_bf16(  \
                    areg[mi][kk], breg[(NB) + 1][kk], acc[(MB) + mi][(NB) + 1], 0, 0, 0); \
            }                                                                        \
        }                                                                            \
        __builtin_amdgcn_s_setprio(0);                                               \
    } while (0)

    // Prologue: tile0 fully + tile1 B0,A0 (issue order matters for vmcnt math)
    STG(0, 1, 0); STG(0, 0, 0); STG(0, 0, 1); STG(0, 1, 1);
    STG(1, 1, 0); STG(1, 0, 0);

    for (int t = 0; t < NT; ++t) {
        const int bp = t & 1;
        // ---- phase 0: stage (t+1).A1; vmcnt guarantees tile t landed ----
        if (t + 1 < NT) STG(t + 1, 0, 1);
        if (t == NT - 1) { asm volatile("s_waitcnt vmcnt(0)" ::: "memory"); }
        else             { asm volatile("s_waitcnt vmcnt(6)" ::: "memory"); }
        BAR();
        ldA(bp, 0);
        ldB01(bp);
        MMQ(0, 0);
        BAR();
        // ---- phase 1 ----
        ldB23(bp);
        if (t + 1 < NT) STG(t + 1, 1, 1);
        BAR();
        MMQ(0, 2);
        BAR();
        // ---- phase 2 ----
        ldA(bp, 1);
        if (t + 2 < NT) STG(t + 2, 1, 0);
        BAR();
        MMQ(4, 0);
        BAR();
        // ---- phase 3 ----
        if (t + 2 < NT) STG(t + 2, 0, 0);
        BAR();
        MMQ(4, 2);
        BAR();
    }
#undef STG
#undef MMQ

    // Epilogue. C/D layout: col = lane&15 (=lr), row = lq*4 + reg.
    if (MODE == 0 || MODE == 2) {
        // Pack C tile into LDS (bijective 16B-group XOR swizzle keyed on row&7),
        // then store with 512 threads x 16B fully-contiguous chunks.
#pragma unroll
        for (int nj = 0; nj < 4; nj++) {
            const int colg = wn * 64 + nj * 16 + lr;
            const float bv = (MODE == 2) ? bias[(size_t)e * 4096 + n0 + colg] : 0.f;
            const int g = colg >> 3, rem = colg & 7;
#pragma unroll
            for (int fi = 0; fi < 8; fi++) {
#pragma unroll
                for (int r = 0; r < 4; r++) {
                    const int row = wm * 128 + fi * 16 + lq * 4 + r;
                    float v = acc[fi][nj][r];
                    if (MODE == 2) v = gelu_fast(v + bv);
                    const int pg = (g & ~7) | ((g ^ row) & 7);
                    smem[row * 256 + pg * 8 + rem] = f2bf(v);
                }
            }
        }
        __syncthreads();
        const int mat = n0 >> 10;
        u16* dst0 = (MODE == 0) ? ((mat == 0) ? out_q : (mat == 1 ? out_k : out_v)) : out_bf;
#pragma unroll
        for (int p = 0; p < 16; p++) {
            const int f = tid + p * 512;
            const int row = f >> 5, g = f & 31;
            const int pg = (g & ~7) | ((g ^ row) & 7);
            const uint4 val = *(const uint4*)&smem[row * 256 + pg * 8];
            if (MODE == 0) {
                const int cc = (n0 + g * 8) & 1023;
                *(uint4*)&dst0[(size_t)(m0 + row) * 1024 + cc] = val;
            } else {
                if (m0 + row < cnt)
                    *(uint4*)&dst0[(size_t)(off + m0 + row) * 4096 + n0 + g * 8] = val;
            }
        }
    } else if (MODE == 3) {
        float* o = ks ? o32b : o32a;
#pragma unroll
        for (int nj = 0; nj < 4; nj++) {
            const int col = n0 + wn * 64 + nj * 16 + lr;
            const float bv = ks ? 0.f : bias[(size_t)e * 1024 + col];
#pragma unroll
            for (int fi = 0; fi < 8; fi++) {
                const int rl0 = m0 + wm * 128 + fi * 16 + lq * 4;
#pragma unroll
                for (int r = 0; r < 4; r++)
                    if (rl0 + r < cnt)
                        o[(size_t)(off + rl0 + r) * 1024 + col] = acc[fi][nj][r] + bv;
            }
        }
    }
}

// ---------------------------------------------------------------------------
// Flash attention, bf16 MFMA. Grid (S/64, H, B), 256 threads = 4 waves.
// Output packed through ps (LDS) for full-line coalesced stores.
// ---------------------------------------------------------------------------
__global__ __launch_bounds__(256) void attn_mfma(const u16* __restrict__ qb,
                                                 const u16* __restrict__ kb,
                                                 const u16* __restrict__ vt,
                                                 u16* __restrict__ aob) {
    __shared__ u16 qs[64][72], ks[64][72], vs[64][72], ps[64][72];
    const int q0 = blockIdx.x * 64, h = blockIdx.y, b = blockIdx.z;
    const int tid = threadIdx.x, w = tid >> 6, lane = tid & 63;
    const int lr = lane & 15, lq = lane >> 4;
    const int ms = w * 16;
    const size_t tok0 = (size_t)b * Sc;

#pragma unroll
    for (int i = 0; i < 2; i++) {
        int c = tid + i * 256;
        int row = c >> 3, d8 = (c & 7) * 8;
        *(uint4*)&qs[row][d8] = *(const uint4*)(qb + (tok0 + q0 + row) * 1024 + h * 64 + d8);
    }
    __syncthreads();
    short8 qa[2];
    qa[0] = *(const short8*)&qs[ms + lr][lq * 8];
    qa[1] = *(const short8*)&qs[ms + lr][32 + lq * 8];

    floatx4 oacc[4];
    float m_r[4], l_r[4];
#pragma unroll
    for (int d4 = 0; d4 < 4; d4++) oacc[d4] = (floatx4){0.f, 0.f, 0.f, 0.f};
#pragma unroll
    for (int r = 0; r < 4; r++) { m_r[r] = -1e30f; l_r[r] = 0.f; }

    for (int kt = 0; kt < Sc / 64; kt++) {
        int k0 = kt * 64;
        __syncthreads();
#pragma unroll
        for (int i = 0; i < 2; i++) {
            int c = tid + i * 256;
            int row = c >> 3, d8 = (c & 7) * 8;
            *(uint4*)&ks[row][d8] = *(const uint4*)(kb + (tok0 + k0 + row) * 1024 + h * 64 + d8);
            *(uint4*)&vs[row][d8] = *(const uint4*)(vt + (size_t)(h * 64 + row) * 4096 + tok0 + k0 + d8);
        }
        __syncthreads();
        floatx4 sfr[4];
#pragma unroll
        for (int j4 = 0; j4 < 4; j4++) {
            short8 kf0 = *(const short8*)&ks[j4 * 16 + lr][lq * 8];
            short8 kf1 = *(const short8*)&ks[j4 * 16 + lr][32 + lq * 8];
            floatx4 sa = (floatx4){0.f, 0.f, 0.f, 0.f};
            sa = __builtin_amdgcn_mfma_f32_16x16x32_bf16(qa[0], kf0, sa, 0, 0, 0);
            sa = __builtin_amdgcn_mfma_f32_16x16x32_bf16(qa[1], kf1, sa, 0, 0, 0);
            sfr[j4] = sa * 0.125f;
        }
#pragma unroll
        for (int r = 0; r < 4; r++) {
            float mx = fmaxf(fmaxf(sfr[0][r], sfr[1][r]), fmaxf(sfr[2][r], sfr[3][r]));
            mx = fmaxf(mx, __shfl_xor(mx, 1, 64));
            mx = fmaxf(mx, __shfl_xor(mx, 2, 64));
            mx = fmaxf(mx, __shfl_xor(mx, 4, 64));
            mx = fmaxf(mx, __shfl_xor(mx, 8, 64));
            float mn = fmaxf(m_r[r], mx);
            float alpha = __expf(m_r[r] - mn);
            m_r[r] = mn;
            float rs = 0.f;
#pragma unroll
            for (int j4 = 0; j4 < 4; j4++) {
                float p = __expf(sfr[j4][r] - mn);
                sfr[j4][r] = p;
                rs += p;
            }
            rs += __shfl_xor(rs, 1, 64);
            rs += __shfl_xor(rs, 2, 64);
            rs += __shfl_xor(rs, 4, 64);
            rs += __shfl_xor(rs, 8, 64);
            l_r[r] = l_r[r] * alpha + rs;
#pragma unroll
            for (int d4 = 0; d4 < 4; d4++) oacc[d4][r] *= alpha;
        }
#pragma unroll
        for (int j4 = 0; j4 < 4; j4++)
#pragma unroll
            for (int r = 0; r < 4; r++)
                ps[ms + lq * 4 + r][j4 * 16 + lr] = f2bf(sfr[j4][r]);
        __syncthreads();
        short8 pa0 = *(const short8*)&ps[ms + lr][lq * 8];
        short8 pa1 = *(const short8*)&ps[ms + lr][32 + lq * 8];
#pragma unroll
        for (int d4 = 0; d4 < 4; d4++) {
            short8 vf0 = *(const short8*)&vs[d4 * 16 + lr][lq * 8];
            short8 vf1 = *(const short8*)&vs[d4 * 16 + lr][32 + lq * 8];
            oacc[d4] = __builtin_amdgcn_mfma_f32_16x16x32_bf16(pa0, vf0, oacc[d4], 0, 0, 0);
            oacc[d4] = __builtin_amdgcn_mfma_f32_16x16x32_bf16(pa1, vf1, oacc[d4], 0, 0, 0);
        }
    }
    // Pack O through ps (each wave writes only its own 16 rows), then store
    // 16B-contiguous chunks: 8 lanes cover one row's 128B => full 64B lines.
#pragma unroll
    for (int r = 0; r < 4; r++) {
        float inv = 1.0f / l_r[r];
#pragma unroll
        for (int d4 = 0; d4 < 4; d4++)
            ps[ms + lq * 4 + r][d4 * 16 + lr] = f2bf(oacc[d4][r] * inv);
    }
    __syncthreads();
#pragma unroll
    for (int p = 0; p < 2; p++) {
        int f = tid + p * 256;
        int row = f >> 3, g = f & 7;
        uint4 v = *(const uint4*)&ps[row][g * 8];
        *(uint4*)&aob[(tok0 + q0 + row) * 1024 + h * 64 + g * 8] = v;
    }
}

// ---------------------------------------------------------------------------
// Router, scan, scatter, combine
// ---------------------------------------------------------------------------
__global__ __launch_bounds__(256) void router_kernel(const float* __restrict__ x2,
                                                     const float* __restrict__ Wg,
                                                     int* __restrict__ topi,
                                                     float* __restrict__ topw,
                                                     int* __restrict__ counts) {
    int t = blockIdx.x, tid = threadIdx.x;
    float p[Ec] = {};
    const float* xr = x2 + (size_t)t * Dc;
    for (int k = tid; k < Dc; k += 256) {
        float xv = xr[k];
        const float* wr = Wg + (size_t)k * Ec;
#pragma unroll
        for (int e = 0; e < Ec; e++) p[e] += xv * wr[e];
    }
    __shared__ float red[256 * Ec];
#pragma unroll
    for (int e = 0; e < Ec; e++) red[tid * Ec + e] = p[e];
    __syncthreads();
    for (int off = 128; off > 0; off >>= 1) {
        if (tid < off) {
#pragma unroll
            for (int e = 0; e < Ec; e++) red[tid * Ec + e] += red[(tid + off) * Ec + e];
        }
        __syncthreads();
    }
    if (tid == 0) {
        float l[Ec];
        float mx = -1e30f;
#pragma unroll
        for (int e = 0; e < Ec; e++) { l[e] = red[e]; mx = fmaxf(mx, l[e]); }
#pragma unroll
        for (int e = 0; e < Ec; e++) l[e] = __expf(l[e] - mx);
        int i0 = 0;
#pragma unroll
        for (int e = 1; e < Ec; e++) if (l[e] > l[i0]) i0 = e;
        int i1 = (i0 == 0) ? 1 : 0;
#pragma unroll
        for (int e = 0; e < Ec; e++) if (e != i0 && l[e] > l[i1]) i1 = e;
        float v0 = l[i0], v1 = l[i1];
        float inv = 1.0f / (v0 + v1);
        topi[t * 2 + 0] = i0;
        topi[t * 2 + 1] = i1;
        topw[t * 2 + 0] = v0 * inv;
        topw[t * 2 + 1] = v1 * inv;
        atomicAdd(&counts[i0], 1);
        atomicAdd(&counts[i1], 1);
    }
}

__global__ void zero_small(int* counts, int* cursor) {
    int i = threadIdx.x;
    if (i < Ec) { counts[i] = 0; cursor[i] = 0; }
}

__global__ void scan_kernel(const int* counts, int* offsets) {
    if (threadIdx.x == 0) {
        int s = 0;
        for (int e = 0; e < Ec; e++) { offsets[e] = s; s += counts[e]; }
    }
}

__global__ __launch_bounds__(256) void scatter_kernel(const int* __restrict__ topi,
                                                      const int* __restrict__ offsets,
                                                      int* __restrict__ cursor,
                                                      int* __restrict__ list_tok,
                                                      int* __restrict__ slot_of) {
    int t = blockIdx.x * 256 + threadIdx.x;
    if (t >= NTOK) return;
    for (int s2 = 0; s2 < 2; s2++) {
        int e = topi[t * 2 + s2];
        int p = offsets[e] + atomicAdd(&cursor[e], 1);
        list_tok[p] = t;
        slot_of[t * 2 + s2] = p;
    }
}

__global__ __launch_bounds__(256) void combine_kernel(const float* __restrict__ x2,
                                                      const float* __restrict__ h2a,
                                                      const float* __restrict__ h2b,
                                                      const int* __restrict__ slot_of,
                                                      const float* __restrict__ topw,
                                                      float* __restrict__ out) {
    int t = blockIdx.x, c = threadIdx.x;
    int s0 = slot_of[t * 2], s1 = slot_of[t * 2 + 1];
    float w0 = topw[t * 2], w1 = topw[t * 2 + 1];
    float4 a = ((const float4*)(x2 + (size_t)t * Dc))[c];
    float4 p0 = ((const float4*)(h2a + (size_t)s0 * Dc))[c];
    float4 q0 = ((const float4*)(h2b + (size_t)s0 * Dc))[c];
    float4 p1 = ((const float4*)(h2a + (size_t)s1 * Dc))[c];
    float4 q1 = ((const float4*)(h2b + (size_t)s1 * Dc))[c];
    float4 o;
    o.x = a.x + w0 * (p0.x + q0.x) + w1 * (p1.x + q1.x);
    o.y = a.y + w0 * (p0.y + q0.y) + w1 * (p1.y + q1.y);
    o.z = a.z + w0 * (p0.z + q0.z) + w1 * (p1.z + q1.z);
    o.w = a.w + w0 * (p0.w + q0.w) + w1 * (p1.w + q1.w);
    ((float4*)(out + (size_t)t * Dc))[c] = o;
}

// ---------------------------------------------------------------------------
// Workspace (MB):
//  [0,16) x2 fp32   [16,24) x2b    [24,32) hb
//  [32,38) wqkvT    [38,40) woT
//  [40,48) qb  [48,56) kb  [56,64) vt  [64,72) vb->aob   (reused as h2b later)
//  [72,136) w1T     [136,200) w2T  [200,264) h1  [264,296) h2a
//  [296..) router scratch
// ---------------------------------------------------------------------------
extern "C" void kernel_launch(void* const* d_in, const int* in_sizes, int n_in,
                              void* d_out, int out_size, void* d_ws, size_t ws_size,
                              hipStream_t stream) {
    const float* x    = (const float*)d_in[0];
    const float* ln_g = (const float*)d_in[1];
    const float* ln_b = (const float*)d_in[2];
    const float* Wq   = (const float*)d_in[3];
    const float* Wk   = (const float*)d_in[4];
    const float* Wv   = (const float*)d_in[5];
    const float* Wo   = (const float*)d_in[6];
    const float* Wg   = (const float*)d_in[7];
    const float* W1   = (const float*)d_in[8];
    const float* b1   = (const float*)d_in[9];
    const float* W2   = (const float*)d_in[10];
    const float* b2   = (const float*)d_in[11];
    float* out = (float*)d_out;

    char* ws = (char*)d_ws;
    const size_t MB = 1ull << 20;
    float* x2    = (float*)(ws + 0 * MB);
    u16* x2b     = (u16*)(ws + 16 * MB);
    u16* hb      = (u16*)(ws + 24 * MB);
    u16* wqkvT   = (u16*)(ws + 32 * MB);
    u16* woT     = (u16*)(ws + 38 * MB);
    u16* qb      = (u16*)(ws + 40 * MB);
    u16* kb      = (u16*)(ws + 48 * MB);
    u16* vt      = (u16*)(ws + 56 * MB);
    u16* vb      = (u16*)(ws + 64 * MB);  // dead after btrans; reused as aob
    u16* aob     = (u16*)(ws + 64 * MB);
    float* h2b   = (float*)(ws + 40 * MB);  // reuses qb/kb/vt/aob (dead post-attn)
    u16* w1T     = (u16*)(ws + 72 * MB);
    u16* w2T     = (u16*)(ws + 136 * MB);
    u16* h1      = (u16*)(ws + 200 * MB);
    float* h2    = (float*)(ws + 264 * MB);
    char* sm     = ws + 296 * MB;
    float* topw    = (float*)(sm);
    int*   topi    = (int*)(sm + (1 << 15));
    int*   slot_of = (int*)(sm + 2 * (1 << 15));
    int*   list_tok= (int*)(sm + 3 * (1 << 15));
    int*   counts  = (int*)(sm + 4 * (1 << 15));
    int*   offsets = counts + 64;
    int*   cursor  = counts + 128;

    // weight transpose-casts
    tcast_kernel<<<dim3(16, 16, 1), 256, 0, stream>>>(Wq, wqkvT + 0 * 1024 * 1024, 1024, 1024, 0, 0);
    tcast_kernel<<<dim3(16, 16, 1), 256, 0, stream>>>(Wk, wqkvT + 1 * 1024 * 1024, 1024, 1024, 0, 0);
    tcast_kernel<<<dim3(16, 16, 1), 256, 0, stream>>>(Wv, wqkvT + 2 * 1024 * 1024, 1024, 1024, 0, 0);
    tcast_kernel<<<dim3(16, 16, 1), 256, 0, stream>>>(Wo, woT, 1024, 1024, 0, 0);
    tcast_kernel<<<dim3(64, 16, 8), 256, 0, stream>>>(W1, w1T, 1024, 4096,
                                                      (size_t)1024 * 4096, (size_t)4096 * 1024);
    tcast_kernel<<<dim3(16, 64, 8), 256, 0, stream>>>(W2, w2T, 4096, 1024,
                                                      (size_t)4096 * 1024, (size_t)1024 * 4096);

    // attention
    ln_kernel<<<NTOK, 256, 0, stream>>>(x, ln_g, ln_b, hb);
    gemm256<0><<<dim3(12, 16, 1), 512, 0, stream>>>(hb, wqkvT, 3072, 1024,
                                                    qb, kb, vb, nullptr, nullptr, nullptr,
                                                    nullptr, nullptr, nullptr, nullptr);
    btrans_kernel<<<dim3(16, 64), 256, 0, stream>>>(vb, vt, 4096, 1024);
    attn_mfma<<<dim3(Sc / 64, 16, 2), 256, 0, stream>>>(qb, kb, vt, aob);
    gemm_mfma<1><<<dim3(8, 32), 256, 0, stream>>>(aob, woT, 1024, 1024,
                                                  nullptr, nullptr, nullptr, x, x2, x2b, nullptr,
                                                  nullptr, nullptr, nullptr);

    // routing
    zero_small<<<1, 64, 0, stream>>>(counts, cursor);
    router_kernel<<<NTOK, 256, 0, stream>>>(x2, Wg, topi, topw, counts);
    scan_kernel<<<1, 1, 0, stream>>>(counts, offsets);
    scatter_kernel<<<NTOK / 256, 256, 0, stream>>>(topi, offsets, cursor, list_tok, slot_of);

    // experts
    gemm256<2><<<dim3(16, 16, 8), 512, 0, stream>>>(x2b, w1T, 4096, 1024,
                                                    nullptr, nullptr, nullptr,
                                                    h1, nullptr, nullptr, b1,
                                                    counts, offsets, list_tok);
    gemm256<3><<<dim3(4, 16, 16), 512, 0, stream>>>(h1, w2T, 1024, 4096,
                                                    nullptr, nullptr, nullptr,
                                                    nullptr, h2, h2b, b2,
                                                    counts, offsets, list_tok);
    combine_kernel<<<NTOK, 256, 0, stream>>>(x2, h2, h2b, slot_of, topw, out);
}

// Round 4
// 918.272 us; speedup vs baseline: 1.1665x; 1.0343x over previous
//
#include <hip/hip_runtime.h>
#include <hip/hip_bf16.h>

// AGIFORMERBlock: B=2, S=2048, D=1024, H=16 (dh=64), F=4096, E=8, K=2
constexpr int Sc = 2048;
constexpr int Dc = 1024;
constexpr int Fc = 4096;
constexpr int Ec = 8;
constexpr int NTOK = 4096;  // B*S

typedef __attribute__((ext_vector_type(8))) short short8;
typedef __attribute__((ext_vector_type(4))) float floatx4;
typedef unsigned short u16;

__device__ __forceinline__ u16 f2bf(float f) {
    __hip_bfloat16 h = __float2bfloat16(f);
    return *reinterpret_cast<u16*>(&h);
}

// tanh-gelu via sigmoid identity
__device__ __forceinline__ float gelu_fast(float x) {
    float x2 = x * x;
    float z = x * fmaf(-0.07135481282f, x2, -1.5957691216057308f);
    float e = __expf(z);
    return x * __builtin_amdgcn_rcpf(1.0f + e);
}

// async global->LDS, 16B per lane; LDS dest = wave-uniform base + lane*16
__device__ __forceinline__ void async16(const u16* g, u16* l) {
    __builtin_amdgcn_global_load_lds(
        (const __attribute__((address_space(1))) unsigned int*)g,
        (__attribute__((address_space(3))) unsigned int*)l, 16, 0, 0);
}

#define BAR() asm volatile("s_barrier" ::: "memory")
#define LGKM0_SGB()                                            \
    do {                                                       \
        asm volatile("s_waitcnt lgkmcnt(0)" ::: "memory");     \
        __builtin_amdgcn_sched_barrier(0);                     \
    } while (0)

// ---------------------------------------------------------------------------
// Transpose-cast: src fp32 [R][C] -> dst bf16 [C][R].  Grid (C/64, R/64, Z).
// ---------------------------------------------------------------------------
__global__ __launch_bounds__(256) void tcast_kernel(const float* __restrict__ src,
                                                    u16* __restrict__ dst,
                                                    int R, int C,
                                                    size_t sstride, size_t dstride) {
    __shared__ float t[64][65];
    const float* s = src + (size_t)blockIdx.z * sstride;
    u16* d = dst + (size_t)blockIdx.z * dstride;
    int r0 = blockIdx.y * 64, c0 = blockIdx.x * 64;
    int tid = threadIdx.x;
#pragma unroll
    for (int i = 0; i < 4; i++) {
        int c = tid + i * 256;
        int row = c >> 4, col4 = (c & 15) * 4;
        float4 v = *(const float4*)(s + (size_t)(r0 + row) * C + c0 + col4);
        t[row][col4 + 0] = v.x;
        t[row][col4 + 1] = v.y;
        t[row][col4 + 2] = v.z;
        t[row][col4 + 3] = v.w;
    }
    __syncthreads();
#pragma unroll
    for (int i = 0; i < 2; i++) {
        int c = tid + i * 256;
        int dr = c >> 3, m8 = (c & 7) * 8;
        union { u16 us[8]; uint4 v; } pk;
#pragma unroll
        for (int j = 0; j < 8; j++) pk.us[j] = f2bf(t[m8 + j][dr]);
        *(uint4*)(d + (size_t)(c0 + dr) * R + r0 + m8) = pk.v;
    }
}

// ---------------------------------------------------------------------------
// bf16 transpose: src [R][C] -> dst [C][R]. Grid (C/64, R/64).
// ---------------------------------------------------------------------------
__global__ __launch_bounds__(256) void btrans_kernel(const u16* __restrict__ src,
                                                     u16* __restrict__ dst,
                                                     int R, int C) {
    __shared__ u16 t[64][72];
    int r0 = blockIdx.y * 64, c0 = blockIdx.x * 64;
    int tid = threadIdx.x;
#pragma unroll
    for (int i = 0; i < 2; i++) {
        int c = tid + i * 256;
        int row = c >> 3, s8 = (c & 7) * 8;
        *(uint4*)&t[row][s8] = *(const uint4*)(src + (size_t)(r0 + row) * C + c0 + s8);
    }
    __syncthreads();
#pragma unroll
    for (int i = 0; i < 2; i++) {
        int c = tid + i * 256;
        int row = c >> 3, s8 = (c & 7) * 8;
        union { u16 us[8]; uint4 v; } pk;
#pragma unroll
        for (int j = 0; j < 8; j++) pk.us[j] = t[s8 + j][row];
        *(uint4*)(dst + (size_t)(c0 + row) * R + r0 + s8) = pk.v;
    }
}

// ---------------------------------------------------------------------------
// LayerNorm -> bf16. One block per row, 256 threads, D=1024.
// ---------------------------------------------------------------------------
__global__ __launch_bounds__(256) void ln_kernel(const float* __restrict__ x,
                                                 const float* __restrict__ g,
                                                 const float* __restrict__ b,
                                                 u16* __restrict__ hb) {
    int row = blockIdx.x, tid = threadIdx.x;
    const float* xr = x + (size_t)row * Dc;
    float4 xv = ((const float4*)xr)[tid];
    float s = xv.x + xv.y + xv.z + xv.w;
    float ss = xv.x * xv.x + xv.y * xv.y + xv.z * xv.z + xv.w * xv.w;
    __shared__ float r1[256], r2[256];
    r1[tid] = s; r2[tid] = ss;
    __syncthreads();
    for (int off = 128; off > 0; off >>= 1) {
        if (tid < off) { r1[tid] += r1[tid + off]; r2[tid] += r2[tid + off]; }
        __syncthreads();
    }
    float mean = r1[0] * (1.0f / Dc);
    float var = r2[0] * (1.0f / Dc) - mean * mean;
    float rs = rsqrtf(var + 1e-5f);
    float4 gv = ((const float4*)g)[tid];
    float4 bv = ((const float4*)b)[tid];
    ushort4 o;
    o.x = f2bf((xv.x - mean) * rs * gv.x + bv.x);
    o.y = f2bf((xv.y - mean) * rs * gv.y + bv.y);
    o.z = f2bf((xv.z - mean) * rs * gv.z + bv.z);
    o.w = f2bf((xv.w - mean) * rs * gv.w + bv.w);
    *(ushort4*)(hb + (size_t)row * Dc + tid * 4) = o;
}

// ---------------------------------------------------------------------------
// OLD bf16 MFMA GEMM, m97 structure: kept only for MODE 1 (O-proj + residual).
// ---------------------------------------------------------------------------
template <int MODE>
__global__ __launch_bounds__(256) void gemm_mfma(
    const u16* __restrict__ A, const u16* __restrict__ BT,
    int N, int K,
    u16* __restrict__ out_q, u16* __restrict__ out_k, u16* __restrict__ out_v,
    const float* __restrict__ resid, float* __restrict__ out_f32,
    u16* __restrict__ out_bf, const float* __restrict__ bias,
    const int* __restrict__ counts, const int* __restrict__ offsets,
    const int* __restrict__ list_tok) {
    const int tid = threadIdx.x;
    const int m0 = blockIdx.y * 128, n0 = blockIdx.x * 128;
    __shared__ u16 As[128][32];
    __shared__ u16 Bs[128][32];
    const u16* Bbase = BT;
    const int w = tid >> 6, lane = tid & 63;
    const int wm = (w >> 1) * 64, wn = (w & 1) * 64;
    const int lr = lane & 15, lq = lane >> 4;

    const int rA0 = w * 32 + (lane >> 2), rA1 = rA0 + 16;
    const int gsegu = (((lane & 3) ^ ((lane >> 3) & 3))) * 8;
    size_t ra0 = (size_t)(m0 + rA0) * K;
    size_t ra1 = (size_t)(m0 + rA1) * K;
    const u16* gA0 = A + ra0 + gsegu;
    const u16* gA1 = A + ra1 + gsegu;
    const u16* gB0 = Bbase + (size_t)(n0 + rA0) * K + gsegu;
    const u16* gB1 = Bbase + (size_t)(n0 + rA1) * K + gsegu;
    u16* ldsA0 = &As[w * 32][0];
    u16* ldsA1 = &As[w * 32 + 16][0];
    u16* ldsB0 = &Bs[w * 32][0];
    u16* ldsB1 = &Bs[w * 32 + 16][0];

    const int fs = (lq ^ ((lr >> 1) & 3)) * 8;
    const u16* apt[4];
    const u16* bpt[4];
#pragma unroll
    for (int i = 0; i < 4; i++) {
        apt[i] = &As[wm + i * 16 + lr][fs];
        bpt[i] = &Bs[wn + i * 16 + lr][fs];
    }

    floatx4 acc[4][4];
#pragma unroll
    for (int i = 0; i < 4; i++)
#pragma unroll
        for (int j = 0; j < 4; j++) acc[i][j] = (floatx4){0.f, 0.f, 0.f, 0.f};

    for (int k0 = 0; k0 < K; k0 += 32) {
        async16(gA0 + k0, ldsA0);
        async16(gA1 + k0, ldsA1);
        async16(gB0 + k0, ldsB0);
        async16(gB1 + k0, ldsB1);
        __syncthreads();
        short8 af[4], bfr[4];
#pragma unroll
        for (int i = 0; i < 4; i++) af[i] = *(const short8*)apt[i];
#pragma unroll
        for (int j = 0; j < 4; j++) bfr[j] = *(const short8*)bpt[j];
#pragma unroll
        for (int i = 0; i < 4; i++)
#pragma unroll
            for (int j = 0; j < 4; j++)
                acc[i][j] = __builtin_amdgcn_mfma_f32_16x16x32_bf16(af[i], bfr[j], acc[i][j], 0, 0, 0);
        __syncthreads();
    }

    // MODE 1 epilogue: + residual -> out_f32 (fp32) and out_bf (bf16)
#pragma unroll
    for (int i = 0; i < 4; i++)
#pragma unroll
        for (int j = 0; j < 4; j++) {
            int col = n0 + wn + j * 16 + lr;
            int row0 = m0 + wm + i * 16 + lq * 4;
#pragma unroll
            for (int r = 0; r < 4; r++) {
                size_t idx = (size_t)(row0 + r) * 1024 + col;
                float v = acc[i][j][r] + resid[idx];
                out_f32[idx] = v;
                out_bf[idx] = f2bf(v);
            }
        }
}

// ---------------------------------------------------------------------------
// 256x256 bf16 MFMA GEMM, read-ahead pipelined (R4 restructure).
// 512 threads = 8 waves (2M x 4N), per-wave C = 128x64, BK=64.
// Per tile: boundary vmcnt(4)+BAR; batch ds_reads issued BEFORE their MFMA
// cluster so LDS latency hides under MFMA issue; ONE mid-tile BAR protects
// the 2-tile-deep prefetch (STG t+2 overwrites current buffer's consumed
// halves). STG order per tile = A1,B1,B0,A0 -> boundary vmcnt(4) drains
// exactly tile t. Barriers: 2/tile (was 8/tile).
// MODE 0: QKV fused (N=3072, K=1024)
// MODE 2: MoE GEMM1, gathered A rows; gelu(acc+b1) -> h1 bf16
// MODE 3: MoE GEMM2, split-K=2 (z = e*2+ks); acc(+b2 if ks==0) -> h2a/h2b
// Grid: x = n-block ALWAYS (R2 post-mortem: null-block periodicity must not
// starve XCDs; useful-block stride must not be = 0 mod 8).
// ---------------------------------------------------------------------------
template <int MODE>
__global__ __launch_bounds__(512, 2) void gemm256(
    const u16* __restrict__ A, const u16* __restrict__ BT, int Nn, int Kfull,
    u16* __restrict__ out_q, u16* __restrict__ out_k, u16* __restrict__ out_v,
    u16* __restrict__ out_bf, float* __restrict__ o32a, float* __restrict__ o32b,
    const float* __restrict__ bias,
    const int* __restrict__ counts, const int* __restrict__ offsets,
    const int* __restrict__ list_tok) {
    __shared__ __attribute__((aligned(16))) u16 smem[66048];  // 128KiB tiles + 1KiB toks
    int e = 0, cnt = 0, off = 0, ks = 0;
    const int bm = (int)blockIdx.y;
    const int bn = (int)blockIdx.x;
    if (MODE >= 2) {
        e = (MODE == 3) ? ((int)blockIdx.z >> 1) : (int)blockIdx.z;
        if (MODE == 3) ks = (int)blockIdx.z & 1;
        cnt = counts[e];
        if (bm * 256 >= cnt) return;
        off = offsets[e];
    }
    const int tid = threadIdx.x;
    const int m0 = bm * 256, n0 = bn * 256;
    const int w = tid >> 6, lane = tid & 63;
    const int wm = w >> 2, wn = w & 3;
    const int lr = lane & 15, lq = lane >> 4;
    const int sz8 = (lr & 7) << 3;  // read-side XOR swizzle (u16 units)

    int* toksL = (int*)(smem + 65536);
    if (MODE == 2) {
        if (tid < 256) toksL[tid] = list_tok[off + min(m0 + tid, cnt - 1)];
        __syncthreads();
    }
    const int K = Kfull;
    const int NT = (MODE == 3 ? 2048 : K) / 64;
    const size_t kb = (MODE == 3) ? (size_t)ks * 2048 : 0;
    const u16* Bb = BT + (MODE >= 2 ? (size_t)e * (size_t)Nn * K : (size_t)0);

    // Staging source pointers; global k-slot pre-swizzled so linear LDS
    // writes are readable with the sz8 XOR.
    const u16* srcA[4];
    const u16* srcB[4];
    {
        const int rl8 = w * 8 + (lane >> 3);
        const int sg = ((lane & 7) ^ (lane >> 3)) * 8;
#pragma unroll
        for (int i = 0; i < 4; i++) {
            int rA = i * 64 + rl8;
            size_t gr;
            if (MODE == 2) gr = (size_t)toksL[rA];
            else if (MODE == 3) gr = (size_t)(off + min(m0 + rA, cnt - 1));
            else gr = (size_t)(m0 + rA);
            srcA[i] = A + gr * K + kb + sg;
            srcB[i] = Bb + (size_t)(n0 + rA) * K + kb + sg;
        }
    }

    short8 areg[4][2], breg[4][2];
    floatx4 acc[8][4];
#pragma unroll
    for (int i = 0; i < 8; i++)
#pragma unroll
        for (int j = 0; j < 4; j++) acc[i][j] = (floatx4){0.f, 0.f, 0.f, 0.f};

// stage one half-tile (mat: 0=A 1=B, half h) of K-tile kt: 2 x 16B/thread
#define STG(kt, mat, h)                                                            \
    do {                                                                           \
        u16* _ld = smem + ((kt) & 1) * 32768 + (mat) * 16384 + (h) * 8192 + w * 512; \
        async16(((mat) ? srcB : srcA)[(h) * 2 + 0] + (size_t)(kt) * 64, _ld);      \
        async16(((mat) ? srcB : srcA)[(h) * 2 + 1] + (size_t)(kt) * 64, _ld + 4096); \
    } while (0)

    auto ldA = [&](int bufp, int mq) {
        const u16* ah = smem + bufp * 32768 + wm * 8192 + (mq * 64 + lr) * 64;
#pragma unroll
        for (int mf = 0; mf < 4; mf++)
#pragma unroll
            for (int kk = 0; kk < 2; kk++)
                areg[mf][kk] = *(const short8*)(ah + mf * 1024 + ((kk * 32 + lq * 8) ^ sz8));
    };
    const int bBo = 16384 + (wn >> 1) * 8192 + (wn & 1) * 4096 + lr * 64;
    auto ldB01 = [&](int bufp) {
        const u16* bh = smem + bufp * 32768 + bBo;
#pragma unroll
        for (int kk = 0; kk < 2; kk++) {
            breg[0][kk] = *(const short8*)(bh + ((kk * 32 + lq * 8) ^ sz8));
            breg[1][kk] = *(const short8*)(bh + 1024 + ((kk * 32 + lq * 8) ^ sz8));
        }
    };
    auto ldB23 = [&](int bufp) {
        const u16* bh = smem + bufp * 32768 + bBo;
#pragma unroll
        for (int kk = 0; kk < 2; kk++) {
            breg[2][kk] = *(const short8*)(bh + 2048 + ((kk * 32 + lq * 8) ^ sz8));
            breg[3][kk] = *(const short8*)(bh + 3072 + ((kk * 32 + lq * 8) ^ sz8));
        }
    };

// one C-quadrant x K=64: 16 MFMAs, setprio-wrapped.
#define MMQ(MB, NB)                                                                  \
    do {                                                                             \
        __builtin_amdgcn_s_setprio(1);                                               \
        _Pragma("unroll") for (int kk = 0; kk < 2; kk++) {                           \
            _Pragma("unroll") for (int mi = 0; mi < 4; mi++) {                       \
                acc[(MB) + mi][(NB) + 0] = __builtin_amdgcn_mfma_f32_16x16x32_bf16(  \
                    areg[mi][kk], breg[(NB) + 0][kk], acc[(MB) + mi][(NB) + 0], 0, 0, 0); \
                acc[(MB) + mi][(NB) + 1] = __builtin_amdgcn_mfma_f32_16x16x32_bf16(  \
                    areg[mi][kk], breg[(NB) + 1][kk], acc[(MB) + mi][(NB) + 1], 0, 0, 0); \
            }                                                                        \
        }                                                                            \
        __builtin_amdgcn_s_setprio(0);                                               \
    } while (0)

    // Prologue: tile0 (B0,A0,A1,B1) + tile1 (B0,A0). Boundary vmcnt(4)
    // drains the 8 oldest = exactly one full tile.
    STG(0, 1, 0); STG(0, 0, 0); STG(0, 0, 1); STG(0, 1, 1);
    STG(1, 1, 0); STG(1, 0, 0);

    for (int t = 0; t < NT; ++t) {
        const int bp = t & 1;
        if (t == NT - 1) { asm volatile("s_waitcnt vmcnt(0)" ::: "memory"); }
        else             { asm volatile("s_waitcnt vmcnt(4)" ::: "memory"); }
        BAR();
        // ---- Q0: reads issued, A1-prefetch, wait, then B23 reads fly under MFMA
        ldA(bp, 0);
        ldB01(bp);
        if (t + 1 < NT) STG(t + 1, 0, 1);
        LGKM0_SGB();
        ldB23(bp);
        MMQ(0, 0);
        // ---- Q1
        if (t + 1 < NT) STG(t + 1, 1, 1);
        LGKM0_SGB();
        MMQ(0, 2);
        // ---- mid barrier: all waves' reads of buf bp halves A0/B0 complete
        BAR();
        // ---- Q2: reload areg with mq=1 (t+2 STGs overwrite bp's B0/A0 -
        //      safe: those regions' readers all passed the mid barrier)
        ldA(bp, 1);
        if (t + 2 < NT) STG(t + 2, 1, 0);
        LGKM0_SGB();
        MMQ(4, 0);
        // ---- Q3
        if (t + 2 < NT) STG(t + 2, 0, 0);
        MMQ(4, 2);
    }
#undef STG
#undef MMQ

    // Epilogue. C/D layout: col = lane&15 (=lr), row = lq*4 + reg.
    if (MODE == 0 || MODE == 2) {
#pragma unroll
        for (int nj = 0; nj < 4; nj++) {
            const int colg = wn * 64 + nj * 16 + lr;
            const float bv = (MODE == 2) ? bias[(size_t)e * 4096 + n0 + colg] : 0.f;
            const int g = colg >> 3, rem = colg & 7;
#pragma unroll
            for (int fi = 0; fi < 8; fi++) {
#pragma unroll
                for (int r = 0; r < 4; r++) {
                    const int row = wm * 128 + fi * 16 + lq * 4 + r;
                    float v = acc[fi][nj][r];
                    if (MODE == 2) v = gelu_fast(v + bv);
                    const int pg = (g & ~7) | ((g ^ row) & 7);
                    smem[row * 256 + pg * 8 + rem] = f2bf(v);
                }
            }
        }
        __syncthreads();
        const int mat = n0 >> 10;
        u16* dst0 = (MODE == 0) ? ((mat == 0) ? out_q : (mat == 1 ? out_k : out_v)) : out_bf;
#pragma unroll
        for (int p = 0; p < 16; p++) {
            const int f = tid + p * 512;
            const int row = f >> 5, g = f & 31;
            const int pg = (g & ~7) | ((g ^ row) & 7);
            const uint4 val = *(const uint4*)&smem[row * 256 + pg * 8];
            if (MODE == 0) {
                const int cc = (n0 + g * 8) & 1023;
                *(uint4*)&dst0[(size_t)(m0 + row) * 1024 + cc] = val;
            } else {
                if (m0 + row < cnt)
                    *(uint4*)&dst0[(size_t)(off + m0 + row) * 4096 + n0 + g * 8] = val;
            }
        }
    } else if (MODE == 3) {
        float* o = ks ? o32b : o32a;
#pragma unroll
        for (int nj = 0; nj < 4; nj++) {
            const int col = n0 + wn * 64 + nj * 16 + lr;
            const float bv = ks ? 0.f : bias[(size_t)e * 1024 + col];
#pragma unroll
            for (int fi = 0; fi < 8; fi++) {
                const int rl0 = m0 + wm * 128 + fi * 16 + lq * 4;
#pragma unroll
                for (int r = 0; r < 4; r++)
                    if (rl0 + r < cnt)
                        o[(size_t)(off + rl0 + r) * 1024 + col] = acc[fi][nj][r] + bv;
            }
        }
    }
}

// ---------------------------------------------------------------------------
// Flash attention, bf16 MFMA. Grid (S/64, H, B), 256 threads = 4 waves.
// R4: double-buffered K/V in LDS + async-stage split (issue next-tile global
// loads at phase top, LDS write at bottom); 1 sync per KV-tile (was 3 --
// ps is wave-local: rows ms..ms+15 on both write and read sides).
// ---------------------------------------------------------------------------
__global__ __launch_bounds__(256) void attn_mfma(const u16* __restrict__ qb,
                                                 const u16* __restrict__ kb,
                                                 const u16* __restrict__ vt,
                                                 u16* __restrict__ aob) {
    __shared__ u16 qs[64][72], ks[2][64][72], vs[2][64][72], ps[64][72];
    const int q0 = blockIdx.x * 64, h = blockIdx.y, b = blockIdx.z;
    const int tid = threadIdx.x, w = tid >> 6, lane = tid & 63;
    const int lr = lane & 15, lq = lane >> 4;
    const int ms = w * 16;
    const size_t tok0 = (size_t)b * Sc;
    const int r0 = tid >> 3, d8 = (tid & 7) * 8;      // chunk 0 coords
    const int r1 = (tid + 256) >> 3;                  // chunk 1 row (same d8)

    // Q stage + K/V tile 0 stage
    *(uint4*)&qs[r0][d8] = *(const uint4*)(qb + (tok0 + q0 + r0) * 1024 + h * 64 + d8);
    *(uint4*)&qs[r1][d8] = *(const uint4*)(qb + (tok0 + q0 + r1) * 1024 + h * 64 + d8);
    *(uint4*)&ks[0][r0][d8] = *(const uint4*)(kb + (tok0 + r0) * 1024 + h * 64 + d8);
    *(uint4*)&ks[0][r1][d8] = *(const uint4*)(kb + (tok0 + r1) * 1024 + h * 64 + d8);
    *(uint4*)&vs[0][r0][d8] = *(const uint4*)(vt + (size_t)(h * 64 + r0) * 4096 + tok0 + d8);
    *(uint4*)&vs[0][r1][d8] = *(const uint4*)(vt + (size_t)(h * 64 + r1) * 4096 + tok0 + d8);
    __syncthreads();
    short8 qa[2];
    qa[0] = *(const short8*)&qs[ms + lr][lq * 8];
    qa[1] = *(const short8*)&qs[ms + lr][32 + lq * 8];

    floatx4 oacc[4];
    float m_r[4], l_r[4];
#pragma unroll
    for (int d4 = 0; d4 < 4; d4++) oacc[d4] = (floatx4){0.f, 0.f, 0.f, 0.f};
#pragma unroll
    for (int r = 0; r < 4; r++) { m_r[r] = -1e30f; l_r[r] = 0.f; }

    int cur = 0;
    for (int kt = 0; kt < Sc / 64; kt++) {
        // buf[cur] visible to all waves; buf[cur^1] free for overwrite
        if (kt > 0) __syncthreads();
        // T14 async-stage: issue next tile's global loads now
        uint4 krg0, krg1, vrg0, vrg1;
        const bool more = (kt + 1 < Sc / 64);
        if (more) {
            const int k1 = (kt + 1) * 64;
            krg0 = *(const uint4*)(kb + (tok0 + k1 + r0) * 1024 + h * 64 + d8);
            krg1 = *(const uint4*)(kb + (tok0 + k1 + r1) * 1024 + h * 64 + d8);
            vrg0 = *(const uint4*)(vt + (size_t)(h * 64 + r0) * 4096 + tok0 + k1 + d8);
            vrg1 = *(const uint4*)(vt + (size_t)(h * 64 + r1) * 4096 + tok0 + k1 + d8);
        }
        floatx4 sfr[4];
#pragma unroll
        for (int j4 = 0; j4 < 4; j4++) {
            short8 kf0 = *(const short8*)&ks[cur][j4 * 16 + lr][lq * 8];
            short8 kf1 = *(const short8*)&ks[cur][j4 * 16 + lr][32 + lq * 8];
            floatx4 sa = (floatx4){0.f, 0.f, 0.f, 0.f};
            sa = __builtin_amdgcn_mfma_f32_16x16x32_bf16(qa[0], kf0, sa, 0, 0, 0);
            sa = __builtin_amdgcn_mfma_f32_16x16x32_bf16(qa[1], kf1, sa, 0, 0, 0);
            sfr[j4] = sa * 0.125f;
        }
#pragma unroll
        for (int r = 0; r < 4; r++) {
            float mx = fmaxf(fmaxf(sfr[0][r], sfr[1][r]), fmaxf(sfr[2][r], sfr[3][r]));
            mx = fmaxf(mx, __shfl_xor(mx, 1, 64));
            mx = fmaxf(mx, __shfl_xor(mx, 2, 64));
            mx = fmaxf(mx, __shfl_xor(mx, 4, 64));
            mx = fmaxf(mx, __shfl_xor(mx, 8, 64));
            float mn = fmaxf(m_r[r], mx);
            float alpha = __expf(m_r[r] - mn);
            m_r[r] = mn;
            float rs = 0.f;
#pragma unroll
            for (int j4 = 0; j4 < 4; j4++) {
                float p = __expf(sfr[j4][r] - mn);
                sfr[j4][r] = p;
                rs += p;
            }
            rs += __shfl_xor(rs, 1, 64);
            rs += __shfl_xor(rs, 2, 64);
            rs += __shfl_xor(rs, 4, 64);
            rs += __shfl_xor(rs, 8, 64);
            l_r[r] = l_r[r] * alpha + rs;
#pragma unroll
            for (int d4 = 0; d4 < 4; d4++) oacc[d4][r] *= alpha;
        }
        // P round-trip through ps: wave-local rows, no cross-wave sync needed
#pragma unroll
        for (int j4 = 0; j4 < 4; j4++)
#pragma unroll
            for (int r = 0; r < 4; r++)
                ps[ms + lq * 4 + r][j4 * 16 + lr] = f2bf(sfr[j4][r]);
        short8 pa0 = *(const short8*)&ps[ms + lr][lq * 8];
        short8 pa1 = *(const short8*)&ps[ms + lr][32 + lq * 8];
#pragma unroll
        for (int d4 = 0; d4 < 4; d4++) {
            short8 vf0 = *(const short8*)&vs[cur][d4 * 16 + lr][lq * 8];
            short8 vf1 = *(const short8*)&vs[cur][d4 * 16 + lr][32 + lq * 8];
            oacc[d4] = __builtin_amdgcn_mfma_f32_16x16x32_bf16(pa0, vf0, oacc[d4], 0, 0, 0);
            oacc[d4] = __builtin_amdgcn_mfma_f32_16x16x32_bf16(pa1, vf1, oacc[d4], 0, 0, 0);
        }
        // write next tile into buf^1 (readers of buf^1 finished before this
        // iteration's top sync)
        if (more) {
            *(uint4*)&ks[cur ^ 1][r0][d8] = krg0;
            *(uint4*)&ks[cur ^ 1][r1][d8] = krg1;
            *(uint4*)&vs[cur ^ 1][r0][d8] = vrg0;
            *(uint4*)&vs[cur ^ 1][r1][d8] = vrg1;
        }
        cur ^= 1;
    }
    // Pack O through ps (own rows), sync, then 16B-coalesced stores.
#pragma unroll
    for (int r = 0; r < 4; r++) {
        float inv = 1.0f / l_r[r];
#pragma unroll
        for (int d4 = 0; d4 < 4; d4++)
            ps[ms + lq * 4 + r][d4 * 16 + lr] = f2bf(oacc[d4][r] * inv);
    }
    __syncthreads();
#pragma unroll
    for (int p = 0; p < 2; p++) {
        int f = tid + p * 256;
        int row = f >> 3, g = f & 7;
        uint4 v = *(const uint4*)&ps[row][g * 8];
        *(uint4*)&aob[(tok0 + q0 + row) * 1024 + h * 64 + g * 8] = v;
    }
}

// ---------------------------------------------------------------------------
// Router, scan, scatter, combine
// ---------------------------------------------------------------------------
__global__ __launch_bounds__(256) void router_kernel(const float* __restrict__ x2,
                                                     const float* __restrict__ Wg,
                                                     int* __restrict__ topi,
                                                     float* __restrict__ topw,
                                                     int* __restrict__ counts) {
    int t = blockIdx.x, tid = threadIdx.x;
    float p[Ec] = {};
    const float* xr = x2 + (size_t)t * Dc;
    for (int k = tid; k < Dc; k += 256) {
        float xv = xr[k];
        const float* wr = Wg + (size_t)k * Ec;
#pragma unroll
        for (int e = 0; e < Ec; e++) p[e] += xv * wr[e];
    }
    __shared__ float red[256 * Ec];
#pragma unroll
    for (int e = 0; e < Ec; e++) red[tid * Ec + e] = p[e];
    __syncthreads();
    for (int off = 128; off > 0; off >>= 1) {
        if (tid < off) {
#pragma unroll
            for (int e = 0; e < Ec; e++) red[tid * Ec + e] += red[(tid + off) * Ec + e];
        }
        __syncthreads();
    }
    if (tid == 0) {
        float l[Ec];
        float mx = -1e30f;
#pragma unroll
        for (int e = 0; e < Ec; e++) { l[e] = red[e]; mx = fmaxf(mx, l[e]); }
#pragma unroll
        for (int e = 0; e < Ec; e++) l[e] = __expf(l[e] - mx);
        int i0 = 0;
#pragma unroll
        for (int e = 1; e < Ec; e++) if (l[e] > l[i0]) i0 = e;
        int i1 = (i0 == 0) ? 1 : 0;
#pragma unroll
        for (int e = 0; e < Ec; e++) if (e != i0 && l[e] > l[i1]) i1 = e;
        float v0 = l[i0], v1 = l[i1];
        float inv = 1.0f / (v0 + v1);
        topi[t * 2 + 0] = i0;
        topi[t * 2 + 1] = i1;
        topw[t * 2 + 0] = v0 * inv;
        topw[t * 2 + 1] = v1 * inv;
        atomicAdd(&counts[i0], 1);
        atomicAdd(&counts[i1], 1);
    }
}

__global__ void zero_small(int* counts, int* cursor) {
    int i = threadIdx.x;
    if (i < Ec) { counts[i] = 0; cursor[i] = 0; }
}

__global__ void scan_kernel(const int* counts, int* offsets) {
    if (threadIdx.x == 0) {
        int s = 0;
        for (int e = 0; e < Ec; e++) { offsets[e] = s; s += counts[e]; }
    }
}

__global__ __launch_bounds__(256) void scatter_kernel(const int* __restrict__ topi,
                                                      const int* __restrict__ offsets,
                                                      int* __restrict__ cursor,
                                                      int* __restrict__ list_tok,
                                                      int* __restrict__ slot_of) {
    int t = blockIdx.x * 256 + threadIdx.x;
    if (t >= NTOK) return;
    for (int s2 = 0; s2 < 2; s2++) {
        int e = topi[t * 2 + s2];
        int p = offsets[e] + atomicAdd(&cursor[e], 1);
        list_tok[p] = t;
        slot_of[t * 2 + s2] = p;
    }
}

__global__ __launch_bounds__(256) void combine_kernel(const float* __restrict__ x2,
                                                      const float* __restrict__ h2a,
                                                      const float* __restrict__ h2b,
                                                      const int* __restrict__ slot_of,
                                                      const float* __restrict__ topw,
                                                      float* __restrict__ out) {
    int t = blockIdx.x, c = threadIdx.x;
    int s0 = slot_of[t * 2], s1 = slot_of[t * 2 + 1];
    float w0 = topw[t * 2], w1 = topw[t * 2 + 1];
    float4 a = ((const float4*)(x2 + (size_t)t * Dc))[c];
    float4 p0 = ((const float4*)(h2a + (size_t)s0 * Dc))[c];
    float4 q0 = ((const float4*)(h2b + (size_t)s0 * Dc))[c];
    float4 p1 = ((const float4*)(h2a + (size_t)s1 * Dc))[c];
    float4 q1 = ((const float4*)(h2b + (size_t)s1 * Dc))[c];
    float4 o;
    o.x = a.x + w0 * (p0.x + q0.x) + w1 * (p1.x + q1.x);
    o.y = a.y + w0 * (p0.y + q0.y) + w1 * (p1.y + q1.y);
    o.z = a.z + w0 * (p0.z + q0.z) + w1 * (p1.z + q1.z);
    o.w = a.w + w0 * (p0.w + q0.w) + w1 * (p1.w + q1.w);
    ((float4*)(out + (size_t)t * Dc))[c] = o;
}

// ---------------------------------------------------------------------------
// Workspace (MB):
//  [0,16) x2 fp32   [16,24) x2b    [24,32) hb
//  [32,38) wqkvT    [38,40) woT
//  [40,48) qb  [48,56) kb  [56,64) vt  [64,72) vb->aob   (reused as h2b later)
//  [72,136) w1T     [136,200) w2T  [200,264) h1  [264,296) h2a
//  [296..) router scratch
// ---------------------------------------------------------------------------
extern "C" void kernel_launch(void* const* d_in, const int* in_sizes, int n_in,
                              void* d_out, int out_size, void* d_ws, size_t ws_size,
                              hipStream_t stream) {
    const float* x    = (const float*)d_in[0];
    const float* ln_g = (const float*)d_in[1];
    const float* ln_b = (const float*)d_in[2];
    const float* Wq   = (const float*)d_in[3];
    const float* Wk   = (const float*)d_in[4];
    const float* Wv   = (const float*)d_in[5];
    const float* Wo   = (const float*)d_in[6];
    const float* Wg   = (const float*)d_in[7];
    const float* W1   = (const float*)d_in[8];
    const float* b1   = (const float*)d_in[9];
    const float* W2   = (const float*)d_in[10];
    const float* b2   = (const float*)d_in[11];
    float* out = (float*)d_out;

    char* ws = (char*)d_ws;
    const size_t MB = 1ull << 20;
    float* x2    = (float*)(ws + 0 * MB);
    u16* x2b     = (u16*)(ws + 16 * MB);
    u16* hb      = (u16*)(ws + 24 * MB);
    u16* wqkvT   = (u16*)(ws + 32 * MB);
    u16* woT     = (u16*)(ws + 38 * MB);
    u16* qb      = (u16*)(ws + 40 * MB);
    u16* kb      = (u16*)(ws + 48 * MB);
    u16* vt      = (u16*)(ws + 56 * MB);
    u16* vb      = (u16*)(ws + 64 * MB);  // dead after btrans; reused as aob
    u16* aob     = (u16*)(ws + 64 * MB);
    float* h2b   = (float*)(ws + 40 * MB);  // reuses qb/kb/vt/aob (dead post-attn)
    u16* w1T     = (u16*)(ws + 72 * MB);
    u16* w2T     = (u16*)(ws + 136 * MB);
    u16* h1      = (u16*)(ws + 200 * MB);
    float* h2    = (float*)(ws + 264 * MB);
    char* sm     = ws + 296 * MB;
    float* topw    = (float*)(sm);
    int*   topi    = (int*)(sm + (1 << 15));
    int*   slot_of = (int*)(sm + 2 * (1 << 15));
    int*   list_tok= (int*)(sm + 3 * (1 << 15));
    int*   counts  = (int*)(sm + 4 * (1 << 15));
    int*   offsets = counts + 64;
    int*   cursor  = counts + 128;

    // weight transpose-casts
    tcast_kernel<<<dim3(16, 16, 1), 256, 0, stream>>>(Wq, wqkvT + 0 * 1024 * 1024, 1024, 1024, 0, 0);
    tcast_kernel<<<dim3(16, 16, 1), 256, 0, stream>>>(Wk, wqkvT + 1 * 1024 * 1024, 1024, 1024, 0, 0);
    tcast_kernel<<<dim3(16, 16, 1), 256, 0, stream>>>(Wv, wqkvT + 2 * 1024 * 1024, 1024, 1024, 0, 0);
    tcast_kernel<<<dim3(16, 16, 1), 256, 0, stream>>>(Wo, woT, 1024, 1024, 0, 0);
    tcast_kernel<<<dim3(64, 16, 8), 256, 0, stream>>>(W1, w1T, 1024, 4096,
                                                      (size_t)1024 * 4096, (size_t)4096 * 1024);
    tcast_kernel<<<dim3(16, 64, 8), 256, 0, stream>>>(W2, w2T, 4096, 1024,
                                                      (size_t)4096 * 1024, (size_t)1024 * 4096);

    // attention
    ln_kernel<<<NTOK, 256, 0, stream>>>(x, ln_g, ln_b, hb);
    gemm256<0><<<dim3(12, 16, 1), 512, 0, stream>>>(hb, wqkvT, 3072, 1024,
                                                    qb, kb, vb, nullptr, nullptr, nullptr,
                                                    nullptr, nullptr, nullptr, nullptr);
    btrans_kernel<<<dim3(16, 64), 256, 0, stream>>>(vb, vt, 4096, 1024);
    attn_mfma<<<dim3(Sc / 64, 16, 2), 256, 0, stream>>>(qb, kb, vt, aob);
    gemm_mfma<1><<<dim3(8, 32), 256, 0, stream>>>(aob, woT, 1024, 1024,
                                                  nullptr, nullptr, nullptr, x, x2, x2b, nullptr,
                                                  nullptr, nullptr, nullptr);

    // routing
    zero_small<<<1, 64, 0, stream>>>(counts, cursor);
    router_kernel<<<NTOK, 256, 0, stream>>>(x2, Wg, topi, topw, counts);
    scan_kernel<<<1, 1, 0, stream>>>(counts, offsets);
    scatter_kernel<<<NTOK / 256, 256, 0, stream>>>(topi, offsets, cursor, list_tok, slot_of);

    // experts
    gemm256<2><<<dim3(16, 16, 8), 512, 0, stream>>>(x2b, w1T, 4096, 1024,
                                                    nullptr, nullptr, nullptr,
                                                    h1, nullptr, nullptr, b1,
                                                    counts, offsets, list_tok);
    gemm256<3><<<dim3(4, 16, 16), 512, 0, stream>>>(h1, w2T, 1024, 4096,
                                                    nullptr, nullptr, nullptr,
                                                    nullptr, h2, h2b, b2,
                                                    counts, offsets, list_tok);
    combine_kernel<<<NTOK, 256, 0, stream>>>(x2, h2, h2b, slot_of, topw, out);
}